// Round 1
// baseline (400.661 us; speedup 1.0000x reference)
//
#include <hip/hip_runtime.h>
#include <cstdint>

typedef unsigned short u16;
typedef short s8v __attribute__((ext_vector_type(8)));
typedef float f4v __attribute__((ext_vector_type(4)));

// fp32 -> bf16 round-to-nearest-even (bit trick)
__device__ __forceinline__ u16 f2b(float f) {
  uint32_t u = __float_as_uint(f);
  u = (u + 0x7FFFu + ((u >> 16) & 1u)) >> 16;
  return (u16)u;
}

// ---------------------------------------------------------------------------
// Convert kernels
// ---------------------------------------------------------------------------

// x fp32 -> bf16, 4 elems/thread
__global__ void conv_x(const float* __restrict__ x, u16* __restrict__ xb) {
  int i = blockIdx.x * blockDim.x + threadIdx.x;
  float4 v = ((const float4*)x)[i];
  uint2 o;
  o.x = (uint32_t)f2b(v.x) | ((uint32_t)f2b(v.y) << 16);
  o.y = (uint32_t)f2b(v.z) | ((uint32_t)f2b(v.w) << 16);
  ((uint2*)xb)[i] = o;
}

// W [16][1024][64] fp32 -> dst[(h*64+d)][m] bf16 (B^T layout), 64x64 LDS transpose
__global__ void convT_w(const float* __restrict__ W, u16* __restrict__ dst) {
  __shared__ u16 tile[64][65];
  const int m0 = blockIdx.x * 64;
  const int h  = blockIdx.y;
  const int c  = threadIdx.x & 63;
  const int r4 = threadIdx.x >> 6;
  const float* Wh = W + (size_t)h * 65536;
  for (int i = 0; i < 16; ++i) {
    int lm = i * 4 + r4;
    tile[lm][c] = f2b(Wh[(size_t)(m0 + lm) * 64 + c]);   // coalesced read over d
  }
  __syncthreads();
  for (int i = 0; i < 16; ++i) {
    int dd = i * 4 + r4;
    dst[((size_t)h * 64 + dd) * 1024 + m0 + c] = tile[c][dd];  // coalesced write over m
  }
}

// W_O flat [1024 k][1024 m] fp32 -> dst[m][k] bf16 (B^T layout)
__global__ void convT_wo(const float* __restrict__ W, u16* __restrict__ dst) {
  __shared__ u16 tile[64][65];
  const int k0 = blockIdx.x * 64;
  const int m0 = blockIdx.y * 64;
  const int c  = threadIdx.x & 63;
  const int r4 = threadIdx.x >> 6;
  for (int i = 0; i < 16; ++i) {
    int lk = i * 4 + r4;
    tile[lk][c] = f2b(W[(size_t)(k0 + lk) * 1024 + m0 + c]);
  }
  __syncthreads();
  for (int i = 0; i < 16; ++i) {
    int lm = i * 4 + r4;
    dst[(size_t)(m0 + lm) * 1024 + k0 + c] = tile[c][lm];
  }
}

// V columns of QKV [4096][3072] (cols 2048..3071) -> VT[(h*64+d)][token] bf16.
// 64x64 LDS tile transpose; enables 16B vector V-fragment loads in attention.
__global__ void convT_v(const u16* __restrict__ QKV, u16* __restrict__ VT) {
  __shared__ u16 tile[64][65];
  const int r0 = blockIdx.x * 64;   // token rows (0..4095)
  const int c0 = blockIdx.y * 64;   // v-feature cols (0..1023)
  const int c  = threadIdx.x & 63;
  const int r4 = threadIdx.x >> 6;
  for (int i = 0; i < 16; ++i) {
    int lr = i * 4 + r4;
    tile[lr][c] = QKV[(size_t)(r0 + lr) * 3072 + 2048 + c0 + c];  // coalesced read
  }
  __syncthreads();
  for (int i = 0; i < 16; ++i) {
    int lc = i * 4 + r4;
    VT[(size_t)(c0 + lc) * 4096 + r0 + c] = tile[c][lc];          // coalesced write
  }
}

// bqkv[3072] = concat(b_Q, b_K, b_V) flat; bsum[1024] = sum_h b_O[h][m]
__global__ void conv_bias(const float* __restrict__ bQ, const float* __restrict__ bK,
                          const float* __restrict__ bV, const float* __restrict__ bO,
                          float* __restrict__ bqkv, float* __restrict__ bsum) {
  int t = blockIdx.x * 256 + threadIdx.x;
  if (t < 1024)       bqkv[t] = bQ[t];
  else if (t < 2048)  bqkv[t] = bK[t - 1024];
  else if (t < 3072)  bqkv[t] = bV[t - 2048];
  else {
    int m = t - 3072;
    float s = 0.f;
    for (int hh = 0; hh < 16; ++hh) s += bO[hh * 1024 + m];
    bsum[m] = s;
  }
}

// ---------------------------------------------------------------------------
// bf16 MFMA GEMM: C[M][N] = A[M][K] * BT[N][K]^T + bias[col]
// 128x128 block tile, BK=32, 256 threads = 4 waves (2x2), each wave 64x64 (4x4
// mfma_f32_16x16x32_bf16 tiles). LDS rows padded to 40 bf16 (2-way max conflict).
// ---------------------------------------------------------------------------
template<bool OUT_F32>
__global__ void gemm_bt(const u16* __restrict__ A, const u16* __restrict__ BT,
                        const float* __restrict__ bias, void* __restrict__ Cout,
                        int N, int K) {
  __shared__ __align__(16) u16 sA[128 * 40];
  __shared__ __align__(16) u16 sB[128 * 40];
  const int tid  = threadIdx.x;
  const int lane = tid & 63, wave = tid >> 6;
  const int wm = wave >> 1, wn = wave & 1;
  const int lq = lane & 15, quad = lane >> 4;
  const int m0 = blockIdx.y * 128, n0 = blockIdx.x * 128;

  f4v acc[4][4] = {};

  for (int k0 = 0; k0 < K; k0 += 32) {
    __syncthreads();
    // stage A-tile 128x32 and B-tile 128x32 (bf16): 512 16B segs each, 2/thread
    for (int i = 0; i < 2; ++i) {
      int s = tid + i * 256;
      int row = s >> 2, part = s & 3;
      *(uint4*)&sA[row * 40 + part * 8] =
          *(const uint4*)(A + (size_t)(m0 + row) * K + k0 + part * 8);
      *(uint4*)&sB[row * 40 + part * 8] =
          *(const uint4*)(BT + (size_t)(n0 + row) * K + k0 + part * 8);
    }
    __syncthreads();
    s8v af[4], bfr[4];
    for (int i = 0; i < 4; ++i)
      af[i]  = *(const s8v*)&sA[(wm * 64 + i * 16 + lq) * 40 + quad * 8];
    for (int j = 0; j < 4; ++j)
      bfr[j] = *(const s8v*)&sB[(wn * 64 + j * 16 + lq) * 40 + quad * 8];
    for (int i = 0; i < 4; ++i)
      for (int j = 0; j < 4; ++j)
        acc[i][j] = __builtin_amdgcn_mfma_f32_16x16x32_bf16(af[i], bfr[j], acc[i][j], 0, 0, 0);
  }

  // epilogue: C/D layout row = quad*4+r, col = lane&15
  for (int i = 0; i < 4; ++i)
    for (int j = 0; j < 4; ++j) {
      int row = m0 + wm * 64 + i * 16 + quad * 4;
      int col = n0 + wn * 64 + j * 16 + lq;
      float bb = bias[col];
      for (int r = 0; r < 4; ++r) {
        float v = acc[i][j][r] + bb;
        if (OUT_F32) ((float*)Cout)[(size_t)(row + r) * N + col] = v;
        else         ((u16*)Cout)[(size_t)(row + r) * N + col] = f2b(v);
      }
    }
}

// ---------------------------------------------------------------------------
// Flash attention (causal, online softmax).
// 4 waves / block, each wave owns one 16-query tile; KVBLK = 64.
// QKV packed bf16 [4096][3072]: cols 0-1023 Q, 1024-2047 K (h*64+d).
// VT bf16 [(h*64+d)][4096 tokens] -> vector (16B) V B-fragment loads.
// Per-wave private P-tile in LDS; no barriers (single-wave LDS ordering is
// program order). All 4 waves in a block share identical K/V addresses -> L1.
// Causal mask is only ever needed on the LAST chunk of a tile.
// ---------------------------------------------------------------------------
__global__ __launch_bounds__(256, 4) void attn_fwd(const u16* __restrict__ QKV,
                                                   const u16* __restrict__ VT,
                                                   u16* __restrict__ Z) {
  __shared__ __align__(16) u16 sP[4][16 * 72];   // per-wave 16x64 P tile, stride 72
  const int tid  = threadIdx.x;
  const int wave = tid >> 6, lane = tid & 63;
  const int lq = lane & 15, quad = lane >> 4;
  const int b = blockIdx.z, h = blockIdx.y;
  // heavy tiles dispatch first; all 4 waves in a block have the same nchunk
  const int qt = ((int)gridDim.x - 1 - (int)blockIdx.x) * 4 + wave;
  const int q0 = qt * 16;
  const int RS = 3072;
  const u16* base = QKV + (size_t)b * 2048 * RS;
  const u16* Qb  = base + h * 64;
  const u16* Kb  = base + 1024 + h * 64;
  const u16* VTb = VT + (size_t)h * 64 * 4096 + (size_t)b * 2048;
  u16* sPw = sP[wave];

  // Q A-frags: lane holds Q[q0+lq][d = 32*half + quad*8 + j]
  s8v qf0 = *(const s8v*)&Qb[(size_t)(q0 + lq) * RS + quad * 8];
  s8v qf1 = *(const s8v*)&Qb[(size_t)(q0 + lq) * RS + 32 + quad * 8];

  f4v zacc[4] = {};                      // dc (d-chunk of 16) x reg(r)
  float mrow[4], lsum[4];
  for (int r = 0; r < 4; ++r) { mrow[r] = -3.0e38f; lsum[r] = 0.f; }

  const int nchunk = q0 / 64 + 1;        // KVBLK = 64
  for (int c = 0; c < nchunk; ++c) {
    const int k0 = c * 64;
    f4v sacc[4] = {};
    // QK^T: 8 MFMA, keys k0 + ks*16 + lq
    __builtin_amdgcn_s_setprio(1);
    for (int ks = 0; ks < 4; ++ks) {
      const u16* kr = &Kb[(size_t)(k0 + ks * 16 + lq) * RS + quad * 8];
      s8v kf0 = *(const s8v*)kr;
      s8v kf1 = *(const s8v*)(kr + 32);
      sacc[ks] = __builtin_amdgcn_mfma_f32_16x16x32_bf16(qf0, kf0, sacc[ks], 0, 0, 0);
      sacc[ks] = __builtin_amdgcn_mfma_f32_16x16x32_bf16(qf1, kf1, sacc[ks], 0, 0, 0);
    }
    __builtin_amdgcn_s_setprio(0);

    // scores in C layout: row q = q0+quad*4+r, col key = k0+ks*16+lq
    float s[4][4];
    const int qrow = q0 + quad * 4;
    if (c == nchunk - 1) {               // only the last chunk crosses the diagonal
      for (int ks = 0; ks < 4; ++ks)
        for (int r = 0; r < 4; ++r) {
          s[ks][r] = sacc[ks][r] * 0.125f;
          if (k0 + ks * 16 + lq > qrow + r) s[ks][r] = -3.0e38f;
        }
    } else {
      for (int ks = 0; ks < 4; ++ks)
        for (int r = 0; r < 4; ++r) s[ks][r] = sacc[ks][r] * 0.125f;
    }

    // row max over 16 regs + 16 lanes
    float t[4];
    for (int r = 0; r < 4; ++r)
      t[r] = fmaxf(fmaxf(s[0][r], s[1][r]), fmaxf(s[2][r], s[3][r]));
    for (int off = 1; off < 16; off <<= 1)
      for (int r = 0; r < 4; ++r) t[r] = fmaxf(t[r], __shfl_xor(t[r], off, 64));

    // online-softmax update (p computed in place over s)
    float alpha[4], u[4];
    for (int r = 0; r < 4; ++r) {
      float mnew = fmaxf(mrow[r], t[r]);
      alpha[r] = __expf(mrow[r] - mnew);
      mrow[r] = mnew;
      u[r] = 0.f;
    }
    for (int ks = 0; ks < 4; ++ks)
      for (int r = 0; r < 4; ++r) {
        s[ks][r] = __expf(s[ks][r] - mrow[r]);
        u[r] += s[ks][r];
      }
    for (int off = 1; off < 16; off <<= 1)
      for (int r = 0; r < 4; ++r) u[r] += __shfl_xor(u[r], off, 64);
    for (int r = 0; r < 4; ++r) lsum[r] = lsum[r] * alpha[r] + u[r];
    for (int dc = 0; dc < 4; ++dc)
      for (int r = 0; r < 4; ++r) zacc[dc][r] *= alpha[r];

    // P: C layout -> per-wave LDS (16 rows x 64 keys, stride 72; <=2-way banks)
    for (int ks = 0; ks < 4; ++ks)
      for (int r = 0; r < 4; ++r)
        sPw[(quad * 4 + r) * 72 + ks * 16 + lq] = f2b(s[ks][r]);

    // P A-frags: lane holds P[q=lq][k = 32*half + quad*8 + j]
    s8v pf0 = *(const s8v*)&sPw[lq * 72 + quad * 8];
    s8v pf1 = *(const s8v*)&sPw[lq * 72 + 32 + quad * 8];
    // V B-frags from VT: 16B vector loads, lane holds V[k][d=dc*16+lq]
    __builtin_amdgcn_s_setprio(1);
    for (int dc = 0; dc < 4; ++dc) {
      const u16* vr = &VTb[(size_t)(dc * 16 + lq) * 4096 + k0 + quad * 8];
      s8v vf0 = *(const s8v*)vr;
      s8v vf1 = *(const s8v*)(vr + 32);
      zacc[dc] = __builtin_amdgcn_mfma_f32_16x16x32_bf16(pf0, vf0, zacc[dc], 0, 0, 0);
      zacc[dc] = __builtin_amdgcn_mfma_f32_16x16x32_bf16(pf1, vf1, zacc[dc], 0, 0, 0);
    }
    __builtin_amdgcn_s_setprio(0);
  }

  float inv[4];
  for (int r = 0; r < 4; ++r) inv[r] = 1.0f / lsum[r];
  for (int dc = 0; dc < 4; ++dc)
    for (int r = 0; r < 4; ++r) {
      size_t row = (size_t)b * 2048 + q0 + quad * 4 + r;
      Z[row * 1024 + h * 64 + dc * 16 + lq] = f2b(zacc[dc][r] * inv[r]);
    }
}

// ---------------------------------------------------------------------------
// Launch
// ---------------------------------------------------------------------------
extern "C" void kernel_launch(void* const* d_in, const int* in_sizes, int n_in,
                              void* d_out, int out_size, void* d_ws, size_t ws_size,
                              hipStream_t stream) {
  const float* x  = (const float*)d_in[0];
  const float* WQ = (const float*)d_in[1];
  const float* bQ = (const float*)d_in[2];
  const float* WK = (const float*)d_in[3];
  const float* bK = (const float*)d_in[4];
  const float* WV = (const float*)d_in[5];
  const float* WO = (const float*)d_in[6];
  const float* bV = (const float*)d_in[7];
  const float* bO = (const float*)d_in[8];
  float* out = (float*)d_out;

  uint8_t* ws = (uint8_t*)d_ws;
  u16*   xb    = (u16*)(ws);                       //  8 MB  [4096][1024] (dead after QKV GEMM)
  u16*   VTv   = (u16*)(ws);                       //  8 MB  [1024][4096] V^T (reuses xb)
  u16*   WTqkv = (u16*)(ws + 8388608);             //  6 MB  [3072][1024]
  u16*   WOT   = (u16*)(ws + 14680064);            //  2 MB  [1024][1024]
  u16*   QKV   = (u16*)(ws + 16777216);            // 24 MB  [4096][3072]
  u16*   Zb    = (u16*)(ws + 41943040);            //  8 MB  [4096][1024]
  float* bqkv  = (float*)(ws + 50331648);          // 12 KB
  float* bsum  = (float*)(ws + 50343936);          //  4 KB

  conv_x<<<4096, 256, 0, stream>>>(x, xb);
  convT_w<<<dim3(16, 16), 256, 0, stream>>>(WQ, WTqkv);
  convT_w<<<dim3(16, 16), 256, 0, stream>>>(WK, WTqkv + 1024 * 1024);
  convT_w<<<dim3(16, 16), 256, 0, stream>>>(WV, WTqkv + 2048 * 1024);
  convT_wo<<<dim3(16, 16), 256, 0, stream>>>(WO, WOT);
  conv_bias<<<16, 256, 0, stream>>>(bQ, bK, bV, bO, bqkv, bsum);

  // QKV projection: [4096x1024] x [1024x3072] -> bf16 QKV
  gemm_bt<false><<<dim3(24, 32), 256, 0, stream>>>(xb, WTqkv, bqkv, (void*)QKV, 3072, 1024);
  // V transpose (xb is dead now; VT reuses its workspace)
  convT_v<<<dim3(64, 16), 256, 0, stream>>>(QKV, VTv);
  // attention: 32 blocks x 4 waves = 128 q-tiles per (b,h)
  attn_fwd<<<dim3(32, 16, 2), 256, 0, stream>>>(QKV, VTv, Zb);
  // output projection: [4096x1024] x [1024x1024] -> fp32 out (+ sum_h b_O)
  gemm_bt<true><<<dim3(8, 32), 256, 0, stream>>>(Zb, WOT, bsum, (void*)out, 1024, 1024);
}

// Round 2
// 309.769 us; speedup vs baseline: 1.2934x; 1.2934x over previous
//
#include <hip/hip_runtime.h>
#include <cstdint>

typedef unsigned short u16;
typedef short s8v __attribute__((ext_vector_type(8)));
typedef float f4v __attribute__((ext_vector_type(4)));

// fp32 -> bf16 round-to-nearest-even (bit trick)
__device__ __forceinline__ u16 f2b(float f) {
  uint32_t u = __float_as_uint(f);
  u = (u + 0x7FFFu + ((u >> 16) & 1u)) >> 16;
  return (u16)u;
}

// ---------------------------------------------------------------------------
// Convert kernels
// ---------------------------------------------------------------------------

// x fp32 -> bf16, 4 elems/thread
__global__ void conv_x(const float* __restrict__ x, u16* __restrict__ xb) {
  int i = blockIdx.x * blockDim.x + threadIdx.x;
  float4 v = ((const float4*)x)[i];
  uint2 o;
  o.x = (uint32_t)f2b(v.x) | ((uint32_t)f2b(v.y) << 16);
  o.y = (uint32_t)f2b(v.z) | ((uint32_t)f2b(v.w) << 16);
  ((uint2*)xb)[i] = o;
}

// W [16][1024][64] fp32 -> dst[(h*64+d)][m] bf16 (B^T layout), 64x64 LDS transpose
__global__ void convT_w(const float* __restrict__ W, u16* __restrict__ dst) {
  __shared__ u16 tile[64][65];
  const int m0 = blockIdx.x * 64;
  const int h  = blockIdx.y;
  const int c  = threadIdx.x & 63;
  const int r4 = threadIdx.x >> 6;
  const float* Wh = W + (size_t)h * 65536;
  for (int i = 0; i < 16; ++i) {
    int lm = i * 4 + r4;
    tile[lm][c] = f2b(Wh[(size_t)(m0 + lm) * 64 + c]);   // coalesced read over d
  }
  __syncthreads();
  for (int i = 0; i < 16; ++i) {
    int dd = i * 4 + r4;
    dst[((size_t)h * 64 + dd) * 1024 + m0 + c] = tile[c][dd];  // coalesced write over m
  }
}

// W_O flat [1024 k][1024 m] fp32 -> dst[m][k] bf16 (B^T layout)
__global__ void convT_wo(const float* __restrict__ W, u16* __restrict__ dst) {
  __shared__ u16 tile[64][65];
  const int k0 = blockIdx.x * 64;
  const int m0 = blockIdx.y * 64;
  const int c  = threadIdx.x & 63;
  const int r4 = threadIdx.x >> 6;
  for (int i = 0; i < 16; ++i) {
    int lk = i * 4 + r4;
    tile[lk][c] = f2b(W[(size_t)(k0 + lk) * 1024 + m0 + c]);
  }
  __syncthreads();
  for (int i = 0; i < 16; ++i) {
    int lm = i * 4 + r4;
    dst[(size_t)(m0 + lm) * 1024 + k0 + c] = tile[c][lm];
  }
}

// V columns of QKV [4096][3072] (cols 2048..3071) -> VT[(h*64+d)][token] bf16.
// 64x64 LDS tile transpose; enables 16B vector V-fragment loads in attention.
__global__ void convT_v(const u16* __restrict__ QKV, u16* __restrict__ VT) {
  __shared__ u16 tile[64][65];
  const int r0 = blockIdx.x * 64;   // token rows (0..4095)
  const int c0 = blockIdx.y * 64;   // v-feature cols (0..1023)
  const int c  = threadIdx.x & 63;
  const int r4 = threadIdx.x >> 6;
  for (int i = 0; i < 16; ++i) {
    int lr = i * 4 + r4;
    tile[lr][c] = QKV[(size_t)(r0 + lr) * 3072 + 2048 + c0 + c];  // coalesced read
  }
  __syncthreads();
  for (int i = 0; i < 16; ++i) {
    int lc = i * 4 + r4;
    VT[(size_t)(c0 + lc) * 4096 + r0 + c] = tile[c][lc];          // coalesced write
  }
}

// bqkv[3072] = concat(b_Q, b_K, b_V) flat; bsum[1024] = sum_h b_O[h][m]
__global__ void conv_bias(const float* __restrict__ bQ, const float* __restrict__ bK,
                          const float* __restrict__ bV, const float* __restrict__ bO,
                          float* __restrict__ bqkv, float* __restrict__ bsum) {
  int t = blockIdx.x * 256 + threadIdx.x;
  if (t < 1024)       bqkv[t] = bQ[t];
  else if (t < 2048)  bqkv[t] = bK[t - 1024];
  else if (t < 3072)  bqkv[t] = bV[t - 2048];
  else {
    int m = t - 3072;
    float s = 0.f;
    for (int hh = 0; hh < 16; ++hh) s += bO[hh * 1024 + m];
    bsum[m] = s;
  }
}

// ---------------------------------------------------------------------------
// bf16 MFMA GEMM: C[M][N] = A[M][K] * BT[N][K]^T + bias[col]
// 128x128 block tile, BK=32, 256 threads = 4 waves (2x2), each wave 64x64 (4x4
// mfma_f32_16x16x32_bf16 tiles). LDS rows padded to 40 bf16 (2-way max conflict).
// ---------------------------------------------------------------------------
template<bool OUT_F32>
__global__ void gemm_bt(const u16* __restrict__ A, const u16* __restrict__ BT,
                        const float* __restrict__ bias, void* __restrict__ Cout,
                        int N, int K) {
  __shared__ __align__(16) u16 sA[128 * 40];
  __shared__ __align__(16) u16 sB[128 * 40];
  const int tid  = threadIdx.x;
  const int lane = tid & 63, wave = tid >> 6;
  const int wm = wave >> 1, wn = wave & 1;
  const int lq = lane & 15, quad = lane >> 4;
  const int m0 = blockIdx.y * 128, n0 = blockIdx.x * 128;

  f4v acc[4][4] = {};

  for (int k0 = 0; k0 < K; k0 += 32) {
    __syncthreads();
    // stage A-tile 128x32 and B-tile 128x32 (bf16): 512 16B segs each, 2/thread
    for (int i = 0; i < 2; ++i) {
      int s = tid + i * 256;
      int row = s >> 2, part = s & 3;
      *(uint4*)&sA[row * 40 + part * 8] =
          *(const uint4*)(A + (size_t)(m0 + row) * K + k0 + part * 8);
      *(uint4*)&sB[row * 40 + part * 8] =
          *(const uint4*)(BT + (size_t)(n0 + row) * K + k0 + part * 8);
    }
    __syncthreads();
    s8v af[4], bfr[4];
    for (int i = 0; i < 4; ++i)
      af[i]  = *(const s8v*)&sA[(wm * 64 + i * 16 + lq) * 40 + quad * 8];
    for (int j = 0; j < 4; ++j)
      bfr[j] = *(const s8v*)&sB[(wn * 64 + j * 16 + lq) * 40 + quad * 8];
    for (int i = 0; i < 4; ++i)
      for (int j = 0; j < 4; ++j)
        acc[i][j] = __builtin_amdgcn_mfma_f32_16x16x32_bf16(af[i], bfr[j], acc[i][j], 0, 0, 0);
  }

  // epilogue: C/D layout row = quad*4+r, col = lane&15
  for (int i = 0; i < 4; ++i)
    for (int j = 0; j < 4; ++j) {
      int row = m0 + wm * 64 + i * 16 + quad * 4;
      int col = n0 + wn * 64 + j * 16 + lq;
      float bb = bias[col];
      for (int r = 0; r < 4; ++r) {
        float v = acc[i][j][r] + bb;
        if (OUT_F32) ((float*)Cout)[(size_t)(row + r) * N + col] = v;
        else         ((u16*)Cout)[(size_t)(row + r) * N + col] = f2b(v);
      }
    }
}

// ---------------------------------------------------------------------------
// Flash attention (causal, online softmax). 1 wave / 16-query tile, KVBLK=32.
// Round-0 structure + three targeted changes:
//  (a) V via VT[(h*64+d)][token]: 4x 16B vector B-frag loads issued at chunk
//      top (arrive under QK+softmax) instead of 32 scalar loads.
//  (b) next-chunk K register prefetch (kn[4]) -> K latency hidden under
//      previous chunk's softmax+PV; vmcnt never drains in steady state.
//  (c) XCD-aware swizzle: all 128 q-tiles of one (b,h) land on one XCD
//      (id%8 round-robin heuristic) -> K/V stream L2-resident (~2MB/XCD).
// Causal mask applied only on the last chunk (the only one crossing the
// diagonal). Single wave: LDS write->read ordered by program order+lgkmcnt,
// no barriers needed.
// ---------------------------------------------------------------------------
__global__ __launch_bounds__(64) void attn_fwd(const u16* __restrict__ QKV,
                                               const u16* __restrict__ VT,
                                               u16* __restrict__ Z) {
  __shared__ __align__(16) u16 sP[16 * 40];
  const int lane = threadIdx.x;
  const int lq = lane & 15, quad = lane >> 4;

  // swizzle: id -> (xcd, slot); combo g = xcd + 8*(slot/128); qt heavy-first
  const int id   = blockIdx.x;          // 0..4095
  const int xcd  = id & 7;
  const int slot = id >> 3;             // 0..511
  const int g    = xcd + 8 * (slot >> 7);  // 0..31
  const int qt   = 127 - (slot & 127);     // heavy tiles first per XCD stream
  const int h = g & 15, b = g >> 4;
  const int q0 = qt * 16;

  const int RS = 3072;
  const u16* base = QKV + (size_t)b * 2048 * RS;
  const u16* Qb  = base + h * 64;
  const u16* Kb  = base + 1024 + h * 64;
  const u16* VTb = VT + (size_t)h * 64 * 4096 + (size_t)b * 2048;

  // Q A-frags: lane holds Q[q0+lq][d = 32*half + quad*8 + j]
  s8v qf0 = *(const s8v*)&Qb[(size_t)(q0 + lq) * RS + quad * 8];
  s8v qf1 = *(const s8v*)&Qb[(size_t)(q0 + lq) * RS + 32 + quad * 8];

  f4v zacc[4] = {};                      // dc (d-chunk of 16) x reg(r)
  float mrow[4], lsum[4];
  for (int r = 0; r < 4; ++r) { mrow[r] = -3.0e38f; lsum[r] = 0.f; }

#define LOADK(kf_, c_) do {                                                  \
    const int kk0_ = (c_) * 32;                                              \
    const u16* kr0_ = &Kb[(size_t)(kk0_ + lq) * RS + quad * 8];              \
    const u16* kr1_ = &Kb[(size_t)(kk0_ + 16 + lq) * RS + quad * 8];         \
    kf_[0] = *(const s8v*)kr0_;                                              \
    kf_[1] = *(const s8v*)(kr0_ + 32);                                       \
    kf_[2] = *(const s8v*)kr1_;                                              \
    kf_[3] = *(const s8v*)(kr1_ + 32);                                       \
  } while (0)

#define LOADV(vf_, c_) do {                                                  \
    const int kk0_ = (c_) * 32;                                              \
    vf_[0] = *(const s8v*)&VTb[(size_t)(lq)      * 4096 + kk0_ + quad * 8];  \
    vf_[1] = *(const s8v*)&VTb[(size_t)(16 + lq) * 4096 + kk0_ + quad * 8];  \
    vf_[2] = *(const s8v*)&VTb[(size_t)(32 + lq) * 4096 + kk0_ + quad * 8];  \
    vf_[3] = *(const s8v*)&VTb[(size_t)(48 + lq) * 4096 + kk0_ + quad * 8];  \
  } while (0)

  const int nchunk = (q0 + 15) / 32 + 1;
  s8v kf[4], kn[4], vf[4];
  LOADK(kf, 0);

  for (int c = 0; c < nchunk; ++c) {
    const int k0 = c * 32;
    // issue current-chunk V and next-chunk K up front: 8 loads in flight,
    // serviced while QK^T + softmax run.
    LOADV(vf, c);
    if (c + 1 < nchunk) LOADK(kn, c + 1);

    f4v sacc0 = {}, sacc1 = {};
    sacc0 = __builtin_amdgcn_mfma_f32_16x16x32_bf16(qf0, kf[0], sacc0, 0, 0, 0);
    sacc0 = __builtin_amdgcn_mfma_f32_16x16x32_bf16(qf1, kf[1], sacc0, 0, 0, 0);
    sacc1 = __builtin_amdgcn_mfma_f32_16x16x32_bf16(qf0, kf[2], sacc1, 0, 0, 0);
    sacc1 = __builtin_amdgcn_mfma_f32_16x16x32_bf16(qf1, kf[3], sacc1, 0, 0, 0);

    // scores in C layout: row q = q0+quad*4+r, col key = k0(+16)+lq
    float s0[4], s1[4], t[4];
    const int qrow = q0 + quad * 4;
    for (int r = 0; r < 4; ++r) {
      s0[r] = sacc0[r] * 0.125f;
      s1[r] = sacc1[r] * 0.125f;
    }
    if (c + 1 == nchunk) {               // only the last chunk crosses the diagonal
      for (int r = 0; r < 4; ++r) {
        if (k0 + lq > qrow + r)      s0[r] = -3.0e38f;
        if (k0 + 16 + lq > qrow + r) s1[r] = -3.0e38f;
      }
    }
    for (int r = 0; r < 4; ++r) t[r] = fmaxf(s0[r], s1[r]);
    for (int off = 1; off < 16; off <<= 1)
      for (int r = 0; r < 4; ++r) t[r] = fmaxf(t[r], __shfl_xor(t[r], off, 64));

    float alpha[4], p0[4], p1[4], u[4];
    for (int r = 0; r < 4; ++r) {
      float mnew = fmaxf(mrow[r], t[r]);
      alpha[r] = __expf(mrow[r] - mnew);
      p0[r] = __expf(s0[r] - mnew);
      p1[r] = __expf(s1[r] - mnew);
      u[r] = p0[r] + p1[r];
      mrow[r] = mnew;
    }
    for (int off = 1; off < 16; off <<= 1)
      for (int r = 0; r < 4; ++r) u[r] += __shfl_xor(u[r], off, 64);
    for (int r = 0; r < 4; ++r) lsum[r] = lsum[r] * alpha[r] + u[r];
    for (int dc = 0; dc < 4; ++dc)
      for (int r = 0; r < 4; ++r) zacc[dc][r] *= alpha[r];

    // P: C layout -> LDS (16 rows x 32 keys, stride 40)
    for (int r = 0; r < 4; ++r) {
      sP[(quad * 4 + r) * 40 + lq]      = f2b(p0[r]);
      sP[(quad * 4 + r) * 40 + 16 + lq] = f2b(p1[r]);
    }
    // P A-frag: lane holds P[q=lq][k=quad*8+j] (same-wave LDS: program order)
    s8v pf = *(const s8v*)&sP[lq * 40 + quad * 8];

    // PV: V frags arrived during softmax
    for (int dc = 0; dc < 4; ++dc)
      zacc[dc] = __builtin_amdgcn_mfma_f32_16x16x32_bf16(pf, vf[dc], zacc[dc], 0, 0, 0);

    if (c + 1 < nchunk)
      for (int i = 0; i < 4; ++i) kf[i] = kn[i];
  }
#undef LOADK
#undef LOADV

  float inv[4];
  for (int r = 0; r < 4; ++r) inv[r] = 1.0f / lsum[r];
  for (int dc = 0; dc < 4; ++dc)
    for (int r = 0; r < 4; ++r) {
      size_t row = (size_t)b * 2048 + q0 + quad * 4 + r;
      Z[row * 1024 + h * 64 + dc * 16 + lq] = f2b(zacc[dc][r] * inv[r]);
    }
}

// ---------------------------------------------------------------------------
// Launch
// ---------------------------------------------------------------------------
extern "C" void kernel_launch(void* const* d_in, const int* in_sizes, int n_in,
                              void* d_out, int out_size, void* d_ws, size_t ws_size,
                              hipStream_t stream) {
  const float* x  = (const float*)d_in[0];
  const float* WQ = (const float*)d_in[1];
  const float* bQ = (const float*)d_in[2];
  const float* WK = (const float*)d_in[3];
  const float* bK = (const float*)d_in[4];
  const float* WV = (const float*)d_in[5];
  const float* WO = (const float*)d_in[6];
  const float* bV = (const float*)d_in[7];
  const float* bO = (const float*)d_in[8];
  float* out = (float*)d_out;

  uint8_t* ws = (uint8_t*)d_ws;
  u16*   xb    = (u16*)(ws);                       //  8 MB  [4096][1024] (dead after QKV GEMM)
  u16*   VTv   = (u16*)(ws);                       //  8 MB  [1024][4096] V^T (reuses xb)
  u16*   WTqkv = (u16*)(ws + 8388608);             //  6 MB  [3072][1024]
  u16*   WOT   = (u16*)(ws + 14680064);            //  2 MB  [1024][1024]
  u16*   QKV   = (u16*)(ws + 16777216);            // 24 MB  [4096][3072]
  u16*   Zb    = (u16*)(ws + 41943040);            //  8 MB  [4096][1024]
  float* bqkv  = (float*)(ws + 50331648);          // 12 KB
  float* bsum  = (float*)(ws + 50343936);          //  4 KB

  conv_x<<<4096, 256, 0, stream>>>(x, xb);
  convT_w<<<dim3(16, 16), 256, 0, stream>>>(WQ, WTqkv);
  convT_w<<<dim3(16, 16), 256, 0, stream>>>(WK, WTqkv + 1024 * 1024);
  convT_w<<<dim3(16, 16), 256, 0, stream>>>(WV, WTqkv + 2048 * 1024);
  convT_wo<<<dim3(16, 16), 256, 0, stream>>>(WO, WOT);
  conv_bias<<<16, 256, 0, stream>>>(bQ, bK, bV, bO, bqkv, bsum);

  // QKV projection: [4096x1024] x [1024x3072] -> bf16 QKV
  gemm_bt<false><<<dim3(24, 32), 256, 0, stream>>>(xb, WTqkv, bqkv, (void*)QKV, 3072, 1024);
  // V transpose (xb is dead now; VT reuses its workspace)
  convT_v<<<dim3(64, 16), 256, 0, stream>>>(QKV, VTv);
  // attention: 4096 one-wave blocks, XCD-swizzled inside the kernel
  attn_fwd<<<dim3(4096, 1, 1), 64, 0, stream>>>(QKV, VTv, Zb);
  // output projection: [4096x1024] x [1024x1024] -> fp32 out (+ sum_h b_O)
  gemm_bt<true><<<dim3(8, 32), 256, 0, stream>>>(Zb, WOT, bsum, (void*)out, 1024, 1024);
}

// Round 3
// 302.019 us; speedup vs baseline: 1.3266x; 1.0257x over previous
//
#include <hip/hip_runtime.h>
#include <cstdint>

typedef unsigned short u16;
typedef short s8v __attribute__((ext_vector_type(8)));
typedef float f4v __attribute__((ext_vector_type(4)));

// fp32 -> bf16 round-to-nearest-even (bit trick)
__device__ __forceinline__ u16 f2b(float f) {
  uint32_t u = __float_as_uint(f);
  u = (u + 0x7FFFu + ((u >> 16) & 1u)) >> 16;
  return (u16)u;
}

// ---------------------------------------------------------------------------
// Convert kernels
// ---------------------------------------------------------------------------

// x fp32 -> bf16, 4 elems/thread
__global__ void conv_x(const float* __restrict__ x, u16* __restrict__ xb) {
  int i = blockIdx.x * blockDim.x + threadIdx.x;
  float4 v = ((const float4*)x)[i];
  uint2 o;
  o.x = (uint32_t)f2b(v.x) | ((uint32_t)f2b(v.y) << 16);
  o.y = (uint32_t)f2b(v.z) | ((uint32_t)f2b(v.w) << 16);
  ((uint2*)xb)[i] = o;
}

// W [16][1024][64] fp32 -> dst[(h*64+d)][m] bf16 (B^T layout), 64x64 LDS transpose
__global__ void convT_w(const float* __restrict__ W, u16* __restrict__ dst) {
  __shared__ u16 tile[64][65];
  const int m0 = blockIdx.x * 64;
  const int h  = blockIdx.y;
  const int c  = threadIdx.x & 63;
  const int r4 = threadIdx.x >> 6;
  const float* Wh = W + (size_t)h * 65536;
  for (int i = 0; i < 16; ++i) {
    int lm = i * 4 + r4;
    tile[lm][c] = f2b(Wh[(size_t)(m0 + lm) * 64 + c]);   // coalesced read over d
  }
  __syncthreads();
  for (int i = 0; i < 16; ++i) {
    int dd = i * 4 + r4;
    dst[((size_t)h * 64 + dd) * 1024 + m0 + c] = tile[c][dd];  // coalesced write over m
  }
}

// W_O flat [1024 k][1024 m] fp32 -> dst[m][k] bf16 (B^T layout)
__global__ void convT_wo(const float* __restrict__ W, u16* __restrict__ dst) {
  __shared__ u16 tile[64][65];
  const int k0 = blockIdx.x * 64;
  const int m0 = blockIdx.y * 64;
  const int c  = threadIdx.x & 63;
  const int r4 = threadIdx.x >> 6;
  for (int i = 0; i < 16; ++i) {
    int lk = i * 4 + r4;
    tile[lk][c] = f2b(W[(size_t)(k0 + lk) * 1024 + m0 + c]);
  }
  __syncthreads();
  for (int i = 0; i < 16; ++i) {
    int lm = i * 4 + r4;
    dst[(size_t)(m0 + lm) * 1024 + k0 + c] = tile[c][lm];
  }
}

// V columns of QKV [4096][3072] (cols 2048..3071) -> VT[(h*64+d)][token] bf16.
// 64x64 LDS tile transpose; enables 16B vector V-fragment loads in attention.
__global__ void convT_v(const u16* __restrict__ QKV, u16* __restrict__ VT) {
  __shared__ u16 tile[64][65];
  const int r0 = blockIdx.x * 64;   // token rows (0..4095)
  const int c0 = blockIdx.y * 64;   // v-feature cols (0..1023)
  const int c  = threadIdx.x & 63;
  const int r4 = threadIdx.x >> 6;
  for (int i = 0; i < 16; ++i) {
    int lr = i * 4 + r4;
    tile[lr][c] = QKV[(size_t)(r0 + lr) * 3072 + 2048 + c0 + c];  // coalesced read
  }
  __syncthreads();
  for (int i = 0; i < 16; ++i) {
    int lc = i * 4 + r4;
    VT[(size_t)(c0 + lc) * 4096 + r0 + c] = tile[c][lc];          // coalesced write
  }
}

// bqkv[3072] = concat(b_Q, b_K, b_V) flat; bsum[1024] = sum_h b_O[h][m]
__global__ void conv_bias(const float* __restrict__ bQ, const float* __restrict__ bK,
                          const float* __restrict__ bV, const float* __restrict__ bO,
                          float* __restrict__ bqkv, float* __restrict__ bsum) {
  int t = blockIdx.x * 256 + threadIdx.x;
  if (t < 1024)       bqkv[t] = bQ[t];
  else if (t < 2048)  bqkv[t] = bK[t - 1024];
  else if (t < 3072)  bqkv[t] = bV[t - 2048];
  else {
    int m = t - 3072;
    float s = 0.f;
    for (int hh = 0; hh < 16; ++hh) s += bO[hh * 1024 + m];
    bsum[m] = s;
  }
}

// ---------------------------------------------------------------------------
// bf16 MFMA GEMM: C[M][N] = A[M][K] * BT[N][K]^T + bias[col]
// 128x128 block tile, BK=32, 256 threads = 4 waves (2x2), each wave 64x64 (4x4
// mfma_f32_16x16x32_bf16 tiles). LDS rows padded to 40 bf16 (2-way max conflict).
// ---------------------------------------------------------------------------
template<bool OUT_F32>
__global__ void gemm_bt(const u16* __restrict__ A, const u16* __restrict__ BT,
                        const float* __restrict__ bias, void* __restrict__ Cout,
                        int N, int K) {
  __shared__ __align__(16) u16 sA[128 * 40];
  __shared__ __align__(16) u16 sB[128 * 40];
  const int tid  = threadIdx.x;
  const int lane = tid & 63, wave = tid >> 6;
  const int wm = wave >> 1, wn = wave & 1;
  const int lq = lane & 15, quad = lane >> 4;
  const int m0 = blockIdx.y * 128, n0 = blockIdx.x * 128;

  f4v acc[4][4] = {};

  for (int k0 = 0; k0 < K; k0 += 32) {
    __syncthreads();
    // stage A-tile 128x32 and B-tile 128x32 (bf16): 512 16B segs each, 2/thread
    for (int i = 0; i < 2; ++i) {
      int s = tid + i * 256;
      int row = s >> 2, part = s & 3;
      *(uint4*)&sA[row * 40 + part * 8] =
          *(const uint4*)(A + (size_t)(m0 + row) * K + k0 + part * 8);
      *(uint4*)&sB[row * 40 + part * 8] =
          *(const uint4*)(BT + (size_t)(n0 + row) * K + k0 + part * 8);
    }
    __syncthreads();
    s8v af[4], bfr[4];
    for (int i = 0; i < 4; ++i)
      af[i]  = *(const s8v*)&sA[(wm * 64 + i * 16 + lq) * 40 + quad * 8];
    for (int j = 0; j < 4; ++j)
      bfr[j] = *(const s8v*)&sB[(wn * 64 + j * 16 + lq) * 40 + quad * 8];
    for (int i = 0; i < 4; ++i)
      for (int j = 0; j < 4; ++j)
        acc[i][j] = __builtin_amdgcn_mfma_f32_16x16x32_bf16(af[i], bfr[j], acc[i][j], 0, 0, 0);
  }

  // epilogue: C/D layout row = quad*4+r, col = lane&15
  for (int i = 0; i < 4; ++i)
    for (int j = 0; j < 4; ++j) {
      int row = m0 + wm * 64 + i * 16 + quad * 4;
      int col = n0 + wn * 64 + j * 16 + lq;
      float bb = bias[col];
      for (int r = 0; r < 4; ++r) {
        float v = acc[i][j][r] + bb;
        if (OUT_F32) ((float*)Cout)[(size_t)(row + r) * N + col] = v;
        else         ((u16*)Cout)[(size_t)(row + r) * N + col] = f2b(v);
      }
    }
}

// ---------------------------------------------------------------------------
// Flash attention (causal, online softmax). 1 wave / 16-query tile, KVBLK=32.
// Round-2 structure (V via VT vector loads, K prefetch, XCD swizzle) plus:
//  (a) per-lane deferred sum: lsum kept unreduced per-lane inside the loop
//      (alpha is row-uniform -> linear), single 4-stage shuffle after loop.
//  (b) defer-max (THR=8): if __all(lane_max <= mrow+8), skip the max
//      shuffle AND the zacc rescale; p = exp(s - mrow_old) <= e^8, fp32-safe.
//      Steady-state chunk has ZERO cross-lane shuffles.
//  (c) V prefetched one chunk ahead (like K): arrival fully off the path.
//  (d) ping-pong P LDS buffer: chunk c read never orders against chunk c+1
//      writes -> compiler can overlap PV with next QK.
// Causal mask applied only on the last chunk. Single wave: no barriers.
// ---------------------------------------------------------------------------
__global__ __launch_bounds__(64) void attn_fwd(const u16* __restrict__ QKV,
                                               const u16* __restrict__ VT,
                                               u16* __restrict__ Z) {
  __shared__ __align__(16) u16 sP[2][16 * 40];
  const int lane = threadIdx.x;
  const int lq = lane & 15, quad = lane >> 4;

  // swizzle: id -> (xcd, slot); combo g = xcd + 8*(slot/128); qt heavy-first
  const int id   = blockIdx.x;          // 0..4095
  const int xcd  = id & 7;
  const int slot = id >> 3;             // 0..511
  const int g    = xcd + 8 * (slot >> 7);  // 0..31
  const int qt   = 127 - (slot & 127);     // heavy tiles first per XCD stream
  const int h = g & 15, b = g >> 4;
  const int q0 = qt * 16;

  const int RS = 3072;
  const u16* base = QKV + (size_t)b * 2048 * RS;
  const u16* Qb  = base + h * 64;
  const u16* Kb  = base + 1024 + h * 64;
  const u16* VTb = VT + (size_t)h * 64 * 4096 + (size_t)b * 2048;

  // Q A-frags: lane holds Q[q0+lq][d = 32*half + quad*8 + j]
  s8v qf0 = *(const s8v*)&Qb[(size_t)(q0 + lq) * RS + quad * 8];
  s8v qf1 = *(const s8v*)&Qb[(size_t)(q0 + lq) * RS + 32 + quad * 8];

  f4v zacc[4] = {};                      // dc (d-chunk of 16) x reg(r)
  float mrow[4], lsum[4];                // lsum is PER-LANE partial (reduced after loop)
  for (int r = 0; r < 4; ++r) { mrow[r] = -3.0e38f; lsum[r] = 0.f; }

#define LOADK(kf_, c_) do {                                                  \
    const int kk0_ = (c_) * 32;                                              \
    const u16* kr0_ = &Kb[(size_t)(kk0_ + lq) * RS + quad * 8];              \
    const u16* kr1_ = &Kb[(size_t)(kk0_ + 16 + lq) * RS + quad * 8];         \
    kf_[0] = *(const s8v*)kr0_;                                              \
    kf_[1] = *(const s8v*)(kr0_ + 32);                                       \
    kf_[2] = *(const s8v*)kr1_;                                              \
    kf_[3] = *(const s8v*)(kr1_ + 32);                                       \
  } while (0)

#define LOADV(vf_, c_) do {                                                  \
    const int kk0_ = (c_) * 32;                                              \
    vf_[0] = *(const s8v*)&VTb[(size_t)(lq)      * 4096 + kk0_ + quad * 8];  \
    vf_[1] = *(const s8v*)&VTb[(size_t)(16 + lq) * 4096 + kk0_ + quad * 8];  \
    vf_[2] = *(const s8v*)&VTb[(size_t)(32 + lq) * 4096 + kk0_ + quad * 8];  \
    vf_[3] = *(const s8v*)&VTb[(size_t)(48 + lq) * 4096 + kk0_ + quad * 8];  \
  } while (0)

  const int nchunk = (q0 + 15) / 32 + 1;
  s8v kf[4], kn[4], vf[4], vn[4];
  LOADK(kf, 0);
  LOADV(vf, 0);

  for (int c = 0; c < nchunk; ++c) {
    const int k0 = c * 32;
    // issue next-chunk K and V up front: in flight under this chunk's compute
    if (c + 1 < nchunk) { LOADK(kn, c + 1); LOADV(vn, c + 1); }

    f4v sacc0 = {}, sacc1 = {};
    sacc0 = __builtin_amdgcn_mfma_f32_16x16x32_bf16(qf0, kf[0], sacc0, 0, 0, 0);
    sacc0 = __builtin_amdgcn_mfma_f32_16x16x32_bf16(qf1, kf[1], sacc0, 0, 0, 0);
    sacc1 = __builtin_amdgcn_mfma_f32_16x16x32_bf16(qf0, kf[2], sacc1, 0, 0, 0);
    sacc1 = __builtin_amdgcn_mfma_f32_16x16x32_bf16(qf1, kf[3], sacc1, 0, 0, 0);

    // scores in C layout: row q = q0+quad*4+r, col key = k0(+16)+lq
    float s0[4], s1[4];
    const int qrow = q0 + quad * 4;
    for (int r = 0; r < 4; ++r) {
      s0[r] = sacc0[r] * 0.125f;
      s1[r] = sacc1[r] * 0.125f;
    }
    if (c + 1 == nchunk) {               // only the last chunk crosses the diagonal
      for (int r = 0; r < 4; ++r) {
        if (k0 + lq > qrow + r)      s0[r] = -3.0e38f;
        if (k0 + 16 + lq > qrow + r) s1[r] = -3.0e38f;
      }
    }

    // lane-local max + defer-max vote (no DS ops on the skip path)
    float lmax[4];
    bool cond = true;
    for (int r = 0; r < 4; ++r) {
      lmax[r] = fmaxf(s0[r], s1[r]);
      cond = cond && (lmax[r] <= mrow[r] + 8.0f);
    }

    float p0[4], p1[4];
    if (__all(cond)) {
      // skip path: keep old mrow, no shuffle, no rescale
      for (int r = 0; r < 4; ++r) {
        p0[r] = __expf(s0[r] - mrow[r]);
        p1[r] = __expf(s1[r] - mrow[r]);
        lsum[r] += p0[r] + p1[r];
      }
    } else {
      float t[4];
      for (int r = 0; r < 4; ++r) t[r] = lmax[r];
      for (int off = 1; off < 16; off <<= 1)
        for (int r = 0; r < 4; ++r) t[r] = fmaxf(t[r], __shfl_xor(t[r], off, 64));
      float al[4];
      for (int r = 0; r < 4; ++r) {
        float mnew = fmaxf(mrow[r], t[r]);
        al[r] = __expf(mrow[r] - mnew);
        mrow[r] = mnew;
        p0[r] = __expf(s0[r] - mnew);
        p1[r] = __expf(s1[r] - mnew);
        lsum[r] = lsum[r] * al[r] + p0[r] + p1[r];
      }
      for (int dc = 0; dc < 4; ++dc)
        for (int r = 0; r < 4; ++r) zacc[dc][r] *= al[r];
    }

    // P: C layout -> ping-pong LDS (16 rows x 32 keys, stride 40)
    u16* sPc = sP[c & 1];
    for (int r = 0; r < 4; ++r) {
      sPc[(quad * 4 + r) * 40 + lq]      = f2b(p0[r]);
      sPc[(quad * 4 + r) * 40 + 16 + lq] = f2b(p1[r]);
    }
    // P A-frag: lane holds P[q=lq][k=quad*8+j] (same-wave LDS: program order)
    s8v pf = *(const s8v*)&sPc[lq * 40 + quad * 8];

    // PV: V frags arrived during previous chunk
    for (int dc = 0; dc < 4; ++dc)
      zacc[dc] = __builtin_amdgcn_mfma_f32_16x16x32_bf16(pf, vf[dc], zacc[dc], 0, 0, 0);

    if (c + 1 < nchunk)
      for (int i = 0; i < 4; ++i) { kf[i] = kn[i]; vf[i] = vn[i]; }
  }
#undef LOADK
#undef LOADV

  // one-time row-sum reduction (was per-chunk before)
  for (int off = 1; off < 16; off <<= 1)
    for (int r = 0; r < 4; ++r) lsum[r] += __shfl_xor(lsum[r], off, 64);

  float inv[4];
  for (int r = 0; r < 4; ++r) inv[r] = 1.0f / lsum[r];
  for (int dc = 0; dc < 4; ++dc)
    for (int r = 0; r < 4; ++r) {
      size_t row = (size_t)b * 2048 + q0 + quad * 4 + r;
      Z[row * 1024 + h * 64 + dc * 16 + lq] = f2b(zacc[dc][r] * inv[r]);
    }
}

// ---------------------------------------------------------------------------
// Launch
// ---------------------------------------------------------------------------
extern "C" void kernel_launch(void* const* d_in, const int* in_sizes, int n_in,
                              void* d_out, int out_size, void* d_ws, size_t ws_size,
                              hipStream_t stream) {
  const float* x  = (const float*)d_in[0];
  const float* WQ = (const float*)d_in[1];
  const float* bQ = (const float*)d_in[2];
  const float* WK = (const float*)d_in[3];
  const float* bK = (const float*)d_in[4];
  const float* WV = (const float*)d_in[5];
  const float* WO = (const float*)d_in[6];
  const float* bV = (const float*)d_in[7];
  const float* bO = (const float*)d_in[8];
  float* out = (float*)d_out;

  uint8_t* ws = (uint8_t*)d_ws;
  u16*   xb    = (u16*)(ws);                       //  8 MB  [4096][1024] (dead after QKV GEMM)
  u16*   VTv   = (u16*)(ws);                       //  8 MB  [1024][4096] V^T (reuses xb)
  u16*   WTqkv = (u16*)(ws + 8388608);             //  6 MB  [3072][1024]
  u16*   WOT   = (u16*)(ws + 14680064);            //  2 MB  [1024][1024]
  u16*   QKV   = (u16*)(ws + 16777216);            // 24 MB  [4096][3072]
  u16*   Zb    = (u16*)(ws + 41943040);            //  8 MB  [4096][1024]
  float* bqkv  = (float*)(ws + 50331648);          // 12 KB
  float* bsum  = (float*)(ws + 50343936);          //  4 KB

  conv_x<<<4096, 256, 0, stream>>>(x, xb);
  convT_w<<<dim3(16, 16), 256, 0, stream>>>(WQ, WTqkv);
  convT_w<<<dim3(16, 16), 256, 0, stream>>>(WK, WTqkv + 1024 * 1024);
  convT_w<<<dim3(16, 16), 256, 0, stream>>>(WV, WTqkv + 2048 * 1024);
  convT_wo<<<dim3(16, 16), 256, 0, stream>>>(WO, WOT);
  conv_bias<<<16, 256, 0, stream>>>(bQ, bK, bV, bO, bqkv, bsum);

  // QKV projection: [4096x1024] x [1024x3072] -> bf16 QKV
  gemm_bt<false><<<dim3(24, 32), 256, 0, stream>>>(xb, WTqkv, bqkv, (void*)QKV, 3072, 1024);
  // V transpose (xb is dead now; VT reuses its workspace)
  convT_v<<<dim3(64, 16), 256, 0, stream>>>(QKV, VTv);
  // attention: 4096 one-wave blocks, XCD-swizzled inside the kernel
  attn_fwd<<<dim3(4096, 1, 1), 64, 0, stream>>>(QKV, VTv, Zb);
  // output projection: [4096x1024] x [1024x1024] -> fp32 out (+ sum_h b_O)
  gemm_bt<true><<<dim3(8, 32), 256, 0, stream>>>(Zb, WOT, bsum, (void*)out, 1024, 1024);
}

// Round 4
// 299.638 us; speedup vs baseline: 1.3372x; 1.0079x over previous
//
#include <hip/hip_runtime.h>
#include <cstdint>

typedef unsigned short u16;
typedef short s8v __attribute__((ext_vector_type(8)));
typedef float f4v __attribute__((ext_vector_type(4)));

// fp32 -> bf16 round-to-nearest-even (bit trick)
__device__ __forceinline__ u16 f2b(float f) {
  uint32_t u = __float_as_uint(f);
  u = (u + 0x7FFFu + ((u >> 16) & 1u)) >> 16;
  return (u16)u;
}

// pack two f32 -> bf16x2 (RNE) in one instruction (T12 recipe; no builtin)
__device__ __forceinline__ uint32_t pk2(float a, float b) {
  uint32_t r;
  asm("v_cvt_pk_bf16_f32 %0, %1, %2" : "=v"(r) : "v"(a), "v"(b));
  return r;
}

// ---------------------------------------------------------------------------
// Convert kernels
// ---------------------------------------------------------------------------

// x fp32 -> bf16, 4 elems/thread
__global__ void conv_x(const float* __restrict__ x, u16* __restrict__ xb) {
  int i = blockIdx.x * blockDim.x + threadIdx.x;
  float4 v = ((const float4*)x)[i];
  uint2 o;
  o.x = (uint32_t)f2b(v.x) | ((uint32_t)f2b(v.y) << 16);
  o.y = (uint32_t)f2b(v.z) | ((uint32_t)f2b(v.w) << 16);
  ((uint2*)xb)[i] = o;
}

// W [16][1024][64] fp32 -> dst[(h*64+d)][m] bf16 (B^T layout), 64x64 LDS transpose
__global__ void convT_w(const float* __restrict__ W, u16* __restrict__ dst) {
  __shared__ u16 tile[64][65];
  const int m0 = blockIdx.x * 64;
  const int h  = blockIdx.y;
  const int c  = threadIdx.x & 63;
  const int r4 = threadIdx.x >> 6;
  const float* Wh = W + (size_t)h * 65536;
  for (int i = 0; i < 16; ++i) {
    int lm = i * 4 + r4;
    tile[lm][c] = f2b(Wh[(size_t)(m0 + lm) * 64 + c]);   // coalesced read over d
  }
  __syncthreads();
  for (int i = 0; i < 16; ++i) {
    int dd = i * 4 + r4;
    dst[((size_t)h * 64 + dd) * 1024 + m0 + c] = tile[c][dd];  // coalesced write over m
  }
}

// W_O flat [1024 k][1024 m] fp32 -> dst[m][k] bf16 (B^T layout)
__global__ void convT_wo(const float* __restrict__ W, u16* __restrict__ dst) {
  __shared__ u16 tile[64][65];
  const int k0 = blockIdx.x * 64;
  const int m0 = blockIdx.y * 64;
  const int c  = threadIdx.x & 63;
  const int r4 = threadIdx.x >> 6;
  for (int i = 0; i < 16; ++i) {
    int lk = i * 4 + r4;
    tile[lk][c] = f2b(W[(size_t)(k0 + lk) * 1024 + m0 + c]);
  }
  __syncthreads();
  for (int i = 0; i < 16; ++i) {
    int lm = i * 4 + r4;
    dst[(size_t)(m0 + lm) * 1024 + k0 + c] = tile[c][lm];
  }
}

// V columns of QKV [4096][3072] (cols 2048..3071) -> VT[(h*64+d)][token] bf16.
__global__ void convT_v(const u16* __restrict__ QKV, u16* __restrict__ VT) {
  __shared__ u16 tile[64][65];
  const int r0 = blockIdx.x * 64;   // token rows (0..4095)
  const int c0 = blockIdx.y * 64;   // v-feature cols (0..1023)
  const int c  = threadIdx.x & 63;
  const int r4 = threadIdx.x >> 6;
  for (int i = 0; i < 16; ++i) {
    int lr = i * 4 + r4;
    tile[lr][c] = QKV[(size_t)(r0 + lr) * 3072 + 2048 + c0 + c];  // coalesced read
  }
  __syncthreads();
  for (int i = 0; i < 16; ++i) {
    int lc = i * 4 + r4;
    VT[(size_t)(c0 + lc) * 4096 + r0 + c] = tile[c][lc];          // coalesced write
  }
}

// bqkv[3072] = concat(b_Q, b_K, b_V) flat; bsum[1024] = sum_h b_O[h][m]
__global__ void conv_bias(const float* __restrict__ bQ, const float* __restrict__ bK,
                          const float* __restrict__ bV, const float* __restrict__ bO,
                          float* __restrict__ bqkv, float* __restrict__ bsum) {
  int t = blockIdx.x * 256 + threadIdx.x;
  if (t < 1024)       bqkv[t] = bQ[t];
  else if (t < 2048)  bqkv[t] = bK[t - 1024];
  else if (t < 3072)  bqkv[t] = bV[t - 2048];
  else {
    int m = t - 3072;
    float s = 0.f;
    for (int hh = 0; hh < 16; ++hh) s += bO[hh * 1024 + m];
    bsum[m] = s;
  }
}

// ---------------------------------------------------------------------------
// bf16 MFMA GEMM: C[M][N] = (A[M][K] * BT[N][K]^T + bias[col]) * (col<scale_cols ? 0.125 : 1)
// The 0.125 (=1/sqrt(D), exact power of 2 -> lossless in bf16) is folded into
// the Q columns of the QKV projection so attention skips the score scaling.
// ---------------------------------------------------------------------------
template<bool OUT_F32>
__global__ void gemm_bt(const u16* __restrict__ A, const u16* __restrict__ BT,
                        const float* __restrict__ bias, void* __restrict__ Cout,
                        int N, int K, int scale_cols) {
  __shared__ __align__(16) u16 sA[128 * 40];
  __shared__ __align__(16) u16 sB[128 * 40];
  const int tid  = threadIdx.x;
  const int lane = tid & 63, wave = tid >> 6;
  const int wm = wave >> 1, wn = wave & 1;
  const int lq = lane & 15, quad = lane >> 4;
  const int m0 = blockIdx.y * 128, n0 = blockIdx.x * 128;

  f4v acc[4][4] = {};

  for (int k0 = 0; k0 < K; k0 += 32) {
    __syncthreads();
    for (int i = 0; i < 2; ++i) {
      int s = tid + i * 256;
      int row = s >> 2, part = s & 3;
      *(uint4*)&sA[row * 40 + part * 8] =
          *(const uint4*)(A + (size_t)(m0 + row) * K + k0 + part * 8);
      *(uint4*)&sB[row * 40 + part * 8] =
          *(const uint4*)(BT + (size_t)(n0 + row) * K + k0 + part * 8);
    }
    __syncthreads();
    s8v af[4], bfr[4];
    for (int i = 0; i < 4; ++i)
      af[i]  = *(const s8v*)&sA[(wm * 64 + i * 16 + lq) * 40 + quad * 8];
    for (int j = 0; j < 4; ++j)
      bfr[j] = *(const s8v*)&sB[(wn * 64 + j * 16 + lq) * 40 + quad * 8];
    for (int i = 0; i < 4; ++i)
      for (int j = 0; j < 4; ++j)
        acc[i][j] = __builtin_amdgcn_mfma_f32_16x16x32_bf16(af[i], bfr[j], acc[i][j], 0, 0, 0);
  }

  // epilogue: C/D layout row = quad*4+r, col = lane&15
  for (int i = 0; i < 4; ++i)
    for (int j = 0; j < 4; ++j) {
      int row = m0 + wm * 64 + i * 16 + quad * 4;
      int col = n0 + wn * 64 + j * 16 + lq;
      float bb = bias[col];
      float sc = (col < scale_cols) ? 0.125f : 1.0f;
      for (int r = 0; r < 4; ++r) {
        float v = (acc[i][j][r] + bb) * sc;
        if (OUT_F32) ((float*)Cout)[(size_t)(row + r) * N + col] = v;
        else         ((u16*)Cout)[(size_t)(row + r) * N + col] = f2b(v);
      }
    }
}

// ---------------------------------------------------------------------------
// Flash attention (causal, online softmax). 1 wave / 16-query tile, KVBLK=32.
// Round-4 changes over round-3:
//  (a) SWAPPED QK^T: sacc = mfma(K, Q) -> lane holds S[k=quad*4+r][q=lq].
//      Each lane owns ONE q-row => mrow/lsum are scalars, defer-max vote is
//      lane-local, rescale reduce is 2 shuffle stages (was 4).
//  (b) in-register P pack via v_cvt_pk_bf16_f32 -> per chunk LDS traffic is
//      2x ds_write_b64 + 1x ds_read_b128 (was 8x b16 write + read).
//  (c) one-chunk software pipeline: iteration c computes QK(c), then PV(c-1)
//      (P written LAST iteration -> LDS write->read latency spans the QK
//      MFMA block), then softmax(c)+P-write. K/V ping-pong via parameterized
//      STEP calls in a 2-unrolled loop (no register copies, static indices).
//  (d) scores arrive pre-scaled (0.125 folded into Q at the QKV GEMM).
// Causal mask only on the last chunk. Single wave: no barriers.
// ---------------------------------------------------------------------------
__global__ __launch_bounds__(64) void attn_fwd(const u16* __restrict__ QKV,
                                               const u16* __restrict__ VT,
                                               u16* __restrict__ Z) {
  __shared__ __align__(16) u16 sP[2][16 * 40];  // ping-pong P tiles, row stride 40 u16
  const int lane = threadIdx.x;
  const int lq = lane & 15, quad = lane >> 4;

  // XCD swizzle: all 128 q-tiles of one (b,h) on one XCD; heavy tiles first
  const int id   = blockIdx.x;             // 0..4095
  const int xcd  = id & 7;
  const int slot = id >> 3;                // 0..511
  const int g    = xcd + 8 * (slot >> 7);  // 0..31
  const int qt   = 127 - (slot & 127);
  const int h = g & 15, b = g >> 4;
  const int q0 = qt * 16;

  const int RS = 3072;
  const u16* base = QKV + (size_t)b * 2048 * RS;
  const u16* Qb  = base + h * 64;
  const u16* Kb  = base + 1024 + h * 64;
  const u16* VTb = VT + (size_t)h * 64 * 4096 + (size_t)b * 2048;

  // Q frags (B-operand now): lane holds Q[q0+lq][d = 32*half + quad*8 + j]
  s8v qf0 = *(const s8v*)&Qb[(size_t)(q0 + lq) * RS + quad * 8];
  s8v qf1 = *(const s8v*)&Qb[(size_t)(q0 + lq) * RS + 32 + quad * 8];

  f4v zacc[4] = {};                 // Z[q=quad*4+r][d=dc*16+lq]
  float mrow = -3.0e38f, lsum = 0.f;  // scalars: lane owns row q=lq

#define LOADK(kf_, c_) do {                                                  \
    const int kk0_ = (c_) * 32;                                              \
    const u16* kr0_ = &Kb[(size_t)(kk0_ + lq) * RS + quad * 8];              \
    const u16* kr1_ = &Kb[(size_t)(kk0_ + 16 + lq) * RS + quad * 8];         \
    kf_[0] = *(const s8v*)kr0_;                                              \
    kf_[1] = *(const s8v*)(kr0_ + 32);                                       \
    kf_[2] = *(const s8v*)kr1_;                                              \
    kf_[3] = *(const s8v*)(kr1_ + 32);                                       \
  } while (0)

#define LOADV(vf_, c_) do {                                                  \
    const int kk0_ = (c_) * 32;                                              \
    vf_[0] = *(const s8v*)&VTb[(size_t)(lq)      * 4096 + kk0_ + quad * 8];  \
    vf_[1] = *(const s8v*)&VTb[(size_t)(16 + lq) * 4096 + kk0_ + quad * 8];  \
    vf_[2] = *(const s8v*)&VTb[(size_t)(32 + lq) * 4096 + kk0_ + quad * 8];  \
    vf_[3] = *(const s8v*)&VTb[(size_t)(48 + lq) * 4096 + kk0_ + quad * 8];  \
  } while (0)

  const int nchunk = q0 / 32 + 1;

  // softmax of chunk c over swapped-layout scores + packed P write
  auto SMW = [&](int c, f4v sacc0, f4v sacc1) {
    float s0[4], s1[4];
    for (int r = 0; r < 4; ++r) { s0[r] = sacc0[r]; s1[r] = sacc1[r]; }
    if (c + 1 == nchunk) {              // only the last chunk crosses the diagonal
      const int kb = c * 32;
      for (int r = 0; r < 4; ++r) {
        if (kb + quad * 4 + r > q0 + lq)      s0[r] = -3.0e38f;
        if (kb + 16 + quad * 4 + r > q0 + lq) s1[r] = -3.0e38f;
      }
    }
    float lmax = fmaxf(fmaxf(fmaxf(s0[0], s0[1]), fmaxf(s0[2], s0[3])),
                       fmaxf(fmaxf(s1[0], s1[1]), fmaxf(s1[2], s1[3])));
    if (!__all(lmax <= mrow + 8.0f)) {  // rare after warmup (defer-max, THR=8)
      float t = lmax;
      t = fmaxf(t, __shfl_xor(t, 16, 64));
      t = fmaxf(t, __shfl_xor(t, 32, 64));   // row max across the 4 quad-lanes
      float mnew = fmaxf(mrow, t);
      float al = __expf(mrow - mnew);
      mrow = mnew;
      lsum *= al;
      float alr[4];                     // redistribute: zacc rows are quad*4+r
      for (int r = 0; r < 4; ++r) alr[r] = __shfl(al, quad * 4 + r, 16);
      for (int dc = 0; dc < 4; ++dc)
        for (int r = 0; r < 4; ++r) zacc[dc][r] *= alr[r];
    }
    float p0[4], p1[4], acc = 0.f;
    for (int r = 0; r < 4; ++r) {
      p0[r] = __expf(s0[r] - mrow);
      p1[r] = __expf(s1[r] - mrow);
      acc += p0[r] + p1[r];
    }
    lsum += acc;
    uint2 wlo, whi;                     // P[q=lq][k]: pack 8 vals -> 4 dwords
    wlo.x = pk2(p0[0], p0[1]); wlo.y = pk2(p0[2], p0[3]);
    whi.x = pk2(p1[0], p1[1]); whi.y = pk2(p1[2], p1[3]);
    u16* rowp = &sP[c & 1][lq * 40 + quad * 4];
    *(uint2*)rowp        = wlo;         // ds_write_b64, k = quad*4..+3
    *(uint2*)(rowp + 16) = whi;         // ds_write_b64, k = 16+quad*4..+3
  };

  s8v kA[4], kB[4], vA[4], vB[4];
  LOADK(kA, 0);
  LOADV(vA, 0);
  if (nchunk > 1) LOADK(kB, 1);

  { // chunk 0: QK + softmax + P write (PV deferred into the pipeline)
    f4v a0 = {}, a1 = {};
    a0 = __builtin_amdgcn_mfma_f32_16x16x32_bf16(kA[0], qf0, a0, 0, 0, 0);
    a0 = __builtin_amdgcn_mfma_f32_16x16x32_bf16(kA[1], qf1, a0, 0, 0, 0);
    a1 = __builtin_amdgcn_mfma_f32_16x16x32_bf16(kA[2], qf0, a1, 0, 0, 0);
    a1 = __builtin_amdgcn_mfma_f32_16x16x32_bf16(kA[3], qf1, a1, 0, 0, 0);
    SMW(0, a0, a1);
  }

  // pipeline step: QK(c) || PV(c-1) || softmax(c)+write P(c)
  auto STEP = [&](int c, s8v (&kcur)[4], s8v (&knxt)[4],
                  s8v (&vpv)[4], s8v (&vnew)[4]) {
    if (c + 1 < nchunk) LOADK(knxt, c + 1);   // K for next iter
    LOADV(vnew, c);                           // V consumed next iter's PV
    f4v a0 = {}, a1 = {};
    a0 = __builtin_amdgcn_mfma_f32_16x16x32_bf16(kcur[0], qf0, a0, 0, 0, 0);
    a0 = __builtin_amdgcn_mfma_f32_16x16x32_bf16(kcur[1], qf1, a0, 0, 0, 0);
    a1 = __builtin_amdgcn_mfma_f32_16x16x32_bf16(kcur[2], qf0, a1, 0, 0, 0);
    a1 = __builtin_amdgcn_mfma_f32_16x16x32_bf16(kcur[3], qf1, a1, 0, 0, 0);
    // PV(c-1): P written last iteration -> LDS latency hidden under QK
    s8v pf = *(const s8v*)&sP[(c + 1) & 1][lq * 40 + quad * 8];
    for (int dc = 0; dc < 4; ++dc)
      zacc[dc] = __builtin_amdgcn_mfma_f32_16x16x32_bf16(pf, vpv[dc], zacc[dc], 0, 0, 0);
    SMW(c, a0, a1);
  };

  int c = 1;
  for (; c + 1 < nchunk; c += 2) {
    STEP(c,     kB, kA, vA, vB);
    STEP(c + 1, kA, kB, vB, vA);
  }
  if (c < nchunk) STEP(c, kB, kA, vA, vB);

  { // drain: PV(nchunk-1)
    s8v pf = *(const s8v*)&sP[(nchunk - 1) & 1][lq * 40 + quad * 8];
    if ((nchunk - 1) & 1) {
      for (int dc = 0; dc < 4; ++dc)
        zacc[dc] = __builtin_amdgcn_mfma_f32_16x16x32_bf16(pf, vB[dc], zacc[dc], 0, 0, 0);
    } else {
      for (int dc = 0; dc < 4; ++dc)
        zacc[dc] = __builtin_amdgcn_mfma_f32_16x16x32_bf16(pf, vA[dc], zacc[dc], 0, 0, 0);
    }
  }
#undef LOADK
#undef LOADV

  // one-time sum reduction across the 4 quad-lanes of each row
  lsum += __shfl_xor(lsum, 16, 64);
  lsum += __shfl_xor(lsum, 32, 64);
  float inv[4];
  for (int r = 0; r < 4; ++r)
    inv[r] = 1.0f / __shfl(lsum, quad * 4 + r, 16);  // total of row quad*4+r

  for (int dc = 0; dc < 4; ++dc)
    for (int r = 0; r < 4; ++r) {
      size_t row = (size_t)b * 2048 + q0 + quad * 4 + r;
      Z[row * 1024 + h * 64 + dc * 16 + lq] = f2b(zacc[dc][r] * inv[r]);
    }
}

// ---------------------------------------------------------------------------
// Launch
// ---------------------------------------------------------------------------
extern "C" void kernel_launch(void* const* d_in, const int* in_sizes, int n_in,
                              void* d_out, int out_size, void* d_ws, size_t ws_size,
                              hipStream_t stream) {
  const float* x  = (const float*)d_in[0];
  const float* WQ = (const float*)d_in[1];
  const float* bQ = (const float*)d_in[2];
  const float* WK = (const float*)d_in[3];
  const float* bK = (const float*)d_in[4];
  const float* WV = (const float*)d_in[5];
  const float* WO = (const float*)d_in[6];
  const float* bV = (const float*)d_in[7];
  const float* bO = (const float*)d_in[8];
  float* out = (float*)d_out;

  uint8_t* ws = (uint8_t*)d_ws;
  u16*   xb    = (u16*)(ws);                       //  8 MB  [4096][1024] (dead after QKV GEMM)
  u16*   VTv   = (u16*)(ws);                       //  8 MB  [1024][4096] V^T (reuses xb)
  u16*   WTqkv = (u16*)(ws + 8388608);             //  6 MB  [3072][1024]
  u16*   WOT   = (u16*)(ws + 14680064);            //  2 MB  [1024][1024]
  u16*   QKV   = (u16*)(ws + 16777216);            // 24 MB  [4096][3072]
  u16*   Zb    = (u16*)(ws + 41943040);            //  8 MB  [4096][1024]
  float* bqkv  = (float*)(ws + 50331648);          // 12 KB
  float* bsum  = (float*)(ws + 50343936);          //  4 KB

  conv_x<<<4096, 256, 0, stream>>>(x, xb);
  convT_w<<<dim3(16, 16), 256, 0, stream>>>(WQ, WTqkv);
  convT_w<<<dim3(16, 16), 256, 0, stream>>>(WK, WTqkv + 1024 * 1024);
  convT_w<<<dim3(16, 16), 256, 0, stream>>>(WV, WTqkv + 2048 * 1024);
  convT_wo<<<dim3(16, 16), 256, 0, stream>>>(WO, WOT);
  conv_bias<<<16, 256, 0, stream>>>(bQ, bK, bV, bO, bqkv, bsum);

  // QKV projection: Q columns pre-scaled by 0.125 (exact in bf16)
  gemm_bt<false><<<dim3(24, 32), 256, 0, stream>>>(xb, WTqkv, bqkv, (void*)QKV, 3072, 1024, 1024);
  // V transpose (xb dead; VT reuses its workspace)
  convT_v<<<dim3(64, 16), 256, 0, stream>>>(QKV, VTv);
  // attention: 4096 one-wave blocks, XCD-swizzled inside the kernel
  attn_fwd<<<dim3(4096, 1, 1), 64, 0, stream>>>(QKV, VTv, Zb);
  // output projection: [4096x1024] x [1024x1024] -> fp32 out (+ sum_h b_O)
  gemm_bt<true><<<dim3(8, 32), 256, 0, stream>>>(Zb, WOT, bsum, (void*)out, 1024, 1024, 0);
}

// Round 5
// 230.946 us; speedup vs baseline: 1.7349x; 1.2974x over previous
//
#include <hip/hip_runtime.h>
#include <cstdint>

typedef unsigned short u16;
typedef short s8v __attribute__((ext_vector_type(8)));
typedef float f4v __attribute__((ext_vector_type(4)));

// fp32 -> bf16 round-to-nearest-even (bit trick)
__device__ __forceinline__ u16 f2b(float f) {
  uint32_t u = __float_as_uint(f);
  u = (u + 0x7FFFu + ((u >> 16) & 1u)) >> 16;
  return (u16)u;
}

// pack two f32 -> bf16x2 (RNE) in one instruction (T12 recipe; no builtin)
__device__ __forceinline__ uint32_t pk2(float a, float b) {
  uint32_t r;
  asm("v_cvt_pk_bf16_f32 %0, %1, %2" : "=v"(r) : "v"(a), "v"(b));
  return r;
}

// async global->LDS, 16B per lane (wave-uniform LDS base + lane*16 layout)
__device__ __forceinline__ void gload16(const u16* g, u16* l) {
  __builtin_amdgcn_global_load_lds(
      (const __attribute__((address_space(1))) void*)g,
      (__attribute__((address_space(3))) void*)l, 16, 0, 0);
}

// ---------------------------------------------------------------------------
// Convert kernels
// ---------------------------------------------------------------------------

// x fp32 -> bf16, 4 elems/thread
__global__ void conv_x(const float* __restrict__ x, u16* __restrict__ xb) {
  int i = blockIdx.x * blockDim.x + threadIdx.x;
  float4 v = ((const float4*)x)[i];
  uint2 o;
  o.x = (uint32_t)f2b(v.x) | ((uint32_t)f2b(v.y) << 16);
  o.y = (uint32_t)f2b(v.z) | ((uint32_t)f2b(v.w) << 16);
  ((uint2*)xb)[i] = o;
}

// W [16][1024][64] fp32 -> dst[(h*64+d)][m] bf16 (B^T layout), 64x64 LDS transpose
__global__ void convT_w(const float* __restrict__ W, u16* __restrict__ dst) {
  __shared__ u16 tile[64][65];
  const int m0 = blockIdx.x * 64;
  const int h  = blockIdx.y;
  const int c  = threadIdx.x & 63;
  const int r4 = threadIdx.x >> 6;
  const float* Wh = W + (size_t)h * 65536;
  for (int i = 0; i < 16; ++i) {
    int lm = i * 4 + r4;
    tile[lm][c] = f2b(Wh[(size_t)(m0 + lm) * 64 + c]);   // coalesced read over d
  }
  __syncthreads();
  for (int i = 0; i < 16; ++i) {
    int dd = i * 4 + r4;
    dst[((size_t)h * 64 + dd) * 1024 + m0 + c] = tile[c][dd];  // coalesced write over m
  }
}

// W_O flat [1024 k][1024 m] fp32 -> dst[m][k] bf16 (B^T layout)
__global__ void convT_wo(const float* __restrict__ W, u16* __restrict__ dst) {
  __shared__ u16 tile[64][65];
  const int k0 = blockIdx.x * 64;
  const int m0 = blockIdx.y * 64;
  const int c  = threadIdx.x & 63;
  const int r4 = threadIdx.x >> 6;
  for (int i = 0; i < 16; ++i) {
    int lk = i * 4 + r4;
    tile[lk][c] = f2b(W[(size_t)(k0 + lk) * 1024 + m0 + c]);
  }
  __syncthreads();
  for (int i = 0; i < 16; ++i) {
    int lm = i * 4 + r4;
    dst[(size_t)(m0 + lm) * 1024 + k0 + c] = tile[c][lm];
  }
}

// V columns of QKV [4096][3072] (cols 2048..3071) -> VT[(h*64+d)][token] bf16.
__global__ void convT_v(const u16* __restrict__ QKV, u16* __restrict__ VT) {
  __shared__ u16 tile[64][65];
  const int r0 = blockIdx.x * 64;   // token rows (0..4095)
  const int c0 = blockIdx.y * 64;   // v-feature cols (0..1023)
  const int c  = threadIdx.x & 63;
  const int r4 = threadIdx.x >> 6;
  for (int i = 0; i < 16; ++i) {
    int lr = i * 4 + r4;
    tile[lr][c] = QKV[(size_t)(r0 + lr) * 3072 + 2048 + c0 + c];  // coalesced read
  }
  __syncthreads();
  for (int i = 0; i < 16; ++i) {
    int lc = i * 4 + r4;
    VT[(size_t)(c0 + lc) * 4096 + r0 + c] = tile[c][lc];          // coalesced write
  }
}

// bqkv[3072] = concat(b_Q, b_K, b_V) flat; bsum[1024] = sum_h b_O[h][m]
__global__ void conv_bias(const float* __restrict__ bQ, const float* __restrict__ bK,
                          const float* __restrict__ bV, const float* __restrict__ bO,
                          float* __restrict__ bqkv, float* __restrict__ bsum) {
  int t = blockIdx.x * 256 + threadIdx.x;
  if (t < 1024)       bqkv[t] = bQ[t];
  else if (t < 2048)  bqkv[t] = bK[t - 1024];
  else if (t < 3072)  bqkv[t] = bV[t - 2048];
  else {
    int m = t - 3072;
    float s = 0.f;
    for (int hh = 0; hh < 16; ++hh) s += bO[hh * 1024 + m];
    bsum[m] = s;
  }
}

// ---------------------------------------------------------------------------
// bf16 MFMA GEMM: C = (A * BT^T + bias[col]) * (col<scale_cols ? 0.125 : 1)
// 128x128 tile, BK=32, 4 waves. Staging now via global_load_lds width=16
// (async DMA, no VGPR round-trip); LDS linear/unpadded [row][32] so the
// wave-uniform-base + lane*16 destination rule holds. Frag ds_read_b128 is a
// fully-covering 1KB read (16 rows x 64B) -> bank-optimal.
// ---------------------------------------------------------------------------
template<bool OUT_F32>
__global__ void gemm_bt(const u16* __restrict__ A, const u16* __restrict__ BT,
                        const float* __restrict__ bias, void* __restrict__ Cout,
                        int N, int K, int scale_cols) {
  __shared__ __align__(16) u16 sA[128 * 32];
  __shared__ __align__(16) u16 sB[128 * 32];
  const int tid  = threadIdx.x;
  const int lane = tid & 63, wave = tid >> 6;
  const int wm = wave >> 1, wn = wave & 1;
  const int lq = lane & 15, quad = lane >> 4;
  const int m0 = blockIdx.y * 128, n0 = blockIdx.x * 128;

  f4v acc[4][4] = {};

  for (int k0 = 0; k0 < K; k0 += 32) {
    __syncthreads();
    // stage A-tile 128x32 and B-tile 128x32: 4 gload16 per thread,
    // LDS dest linear in s = tid + i*256 -> lane-consecutive 16B
    for (int i = 0; i < 2; ++i) {
      int s = tid + i * 256;
      int row = s >> 2, part = s & 3;
      gload16(A  + (size_t)(m0 + row) * K + k0 + part * 8, &sA[s * 8]);
      gload16(BT + (size_t)(n0 + row) * K + k0 + part * 8, &sB[s * 8]);
    }
    __syncthreads();   // compiler drains vmcnt before barrier
    s8v af[4], bfr[4];
    for (int i = 0; i < 4; ++i)
      af[i]  = *(const s8v*)&sA[(wm * 64 + i * 16 + lq) * 32 + quad * 8];
    for (int j = 0; j < 4; ++j)
      bfr[j] = *(const s8v*)&sB[(wn * 64 + j * 16 + lq) * 32 + quad * 8];
    for (int i = 0; i < 4; ++i)
      for (int j = 0; j < 4; ++j)
        acc[i][j] = __builtin_amdgcn_mfma_f32_16x16x32_bf16(af[i], bfr[j], acc[i][j], 0, 0, 0);
  }

  // epilogue: C/D layout row = quad*4+r, col = lane&15
  for (int i = 0; i < 4; ++i)
    for (int j = 0; j < 4; ++j) {
      int row = m0 + wm * 64 + i * 16 + quad * 4;
      int col = n0 + wn * 64 + j * 16 + lq;
      float bb = bias[col];
      float sc = (col < scale_cols) ? 0.125f : 1.0f;
      for (int r = 0; r < 4; ++r) {
        float v = (acc[i][j][r] + bb) * sc;
        if (OUT_F32) ((float*)Cout)[(size_t)(row + r) * N + col] = v;
        else         ((u16*)Cout)[(size_t)(row + r) * N + col] = f2b(v);
      }
    }
}

// ---------------------------------------------------------------------------
// Flash attention (causal, online softmax). 1 wave handles TWO adjacent
// 16-query tiles (rows qA..qA+31); tiles 2u,2u+1 share nchunk=u+1 and K/V.
// Round-5 changes over round-4:
//  (a) 2 q-tiles/wave: two independent MFMA+softmax chains (2x ILP), shared
//      K/V loads (half the L2 traffic), 2048 blocks.
//  (b) heavy+light CU pairing: slot s<32 -> u=63-s (heavy, dispatched first),
//      s>=32 -> u=s-32 (light). Under round-robin block->CU placement each CU
//      gets u=63-c and u=c per combo -> constant 65 chunks/CU/combo (kills
//      the triangular tail that held occupancy at 25%).
// Per-chunk math identical to round-4 (swapped QK^T, scalar softmax state,
// packed P via v_cvt_pk_bf16_f32, one-chunk software pipeline, defer-max).
// ---------------------------------------------------------------------------
__global__ __launch_bounds__(64, 2) void attn_fwd(const u16* __restrict__ QKV,
                                                  const u16* __restrict__ VT,
                                                  u16* __restrict__ Z) {
  __shared__ __align__(16) u16 sP[2][2][16 * 40];  // [tile][pingpong]
  const int lane = threadIdx.x;
  const int lq = lane & 15, quad = lane >> 4;

  const int id   = blockIdx.x;             // 0..2047
  const int xcd  = id & 7;
  const int slot = id >> 3;                // 0..255 per XCD
  const int g    = xcd + 8 * (slot >> 6);  // combo 0..31 (4 combos per XCD)
  const int s    = slot & 63;
  const int u    = (s < 32) ? (63 - s) : (s - 32);  // heavy+light pairing
  const int h = g & 15, b = g >> 4;
  const int qA = u * 32, qB = qA + 16;
  const int nchunk = u + 1;

  const int RS = 3072;
  const u16* base = QKV + (size_t)b * 2048 * RS;
  const u16* Qb  = base + h * 64;
  const u16* Kb  = base + 1024 + h * 64;
  const u16* VTb = VT + (size_t)h * 64 * 4096 + (size_t)b * 2048;

  // Q frags (B-operand): lane holds Q[q+lq][d = 32*half + quad*8 + j]
  s8v qfA0 = *(const s8v*)&Qb[(size_t)(qA + lq) * RS + quad * 8];
  s8v qfA1 = *(const s8v*)&Qb[(size_t)(qA + lq) * RS + 32 + quad * 8];
  s8v qfB0 = *(const s8v*)&Qb[(size_t)(qB + lq) * RS + quad * 8];
  s8v qfB1 = *(const s8v*)&Qb[(size_t)(qB + lq) * RS + 32 + quad * 8];

  f4v zA[4] = {}, zB[4] = {};
  float mA = -3.0e38f, lA = 0.f, mB = -3.0e38f, lB = 0.f;

#define LOADK(kf_, c_) do {                                                  \
    const int kk0_ = (c_) * 32;                                              \
    const u16* kr0_ = &Kb[(size_t)(kk0_ + lq) * RS + quad * 8];              \
    const u16* kr1_ = &Kb[(size_t)(kk0_ + 16 + lq) * RS + quad * 8];         \
    kf_[0] = *(const s8v*)kr0_;                                              \
    kf_[1] = *(const s8v*)(kr0_ + 32);                                       \
    kf_[2] = *(const s8v*)kr1_;                                              \
    kf_[3] = *(const s8v*)(kr1_ + 32);                                       \
  } while (0)

#define LOADV(vf_, c_) do {                                                  \
    const int kk0_ = (c_) * 32;                                              \
    vf_[0] = *(const s8v*)&VTb[(size_t)(lq)      * 4096 + kk0_ + quad * 8];  \
    vf_[1] = *(const s8v*)&VTb[(size_t)(16 + lq) * 4096 + kk0_ + quad * 8];  \
    vf_[2] = *(const s8v*)&VTb[(size_t)(32 + lq) * 4096 + kk0_ + quad * 8];  \
    vf_[3] = *(const s8v*)&VTb[(size_t)(48 + lq) * 4096 + kk0_ + quad * 8];  \
  } while (0)

  // softmax of chunk c for one tile (swapped layout) + packed P write
  auto SMW = [&](int c, int qt0, float& mrow, float& lsum, f4v (&zacc)[4],
                 u16* sPt, f4v sacc0, f4v sacc1) {
    float s0[4], s1[4];
    for (int r = 0; r < 4; ++r) { s0[r] = sacc0[r]; s1[r] = sacc1[r]; }
    if (c + 1 == nchunk) {              // only the last chunk crosses the diagonal
      const int kb = c * 32;
      for (int r = 0; r < 4; ++r) {
        if (kb + quad * 4 + r > qt0 + lq)      s0[r] = -3.0e38f;
        if (kb + 16 + quad * 4 + r > qt0 + lq) s1[r] = -3.0e38f;
      }
    }
    float lmax = fmaxf(fmaxf(fmaxf(s0[0], s0[1]), fmaxf(s0[2], s0[3])),
                       fmaxf(fmaxf(s1[0], s1[1]), fmaxf(s1[2], s1[3])));
    if (!__all(lmax <= mrow + 8.0f)) {  // rare after warmup (defer-max, THR=8)
      float t = lmax;
      t = fmaxf(t, __shfl_xor(t, 16, 64));
      t = fmaxf(t, __shfl_xor(t, 32, 64));   // row max across the 4 quad-lanes
      float mnew = fmaxf(mrow, t);
      float al = __expf(mrow - mnew);
      mrow = mnew;
      lsum *= al;
      float alr[4];                     // redistribute: zacc rows are quad*4+r
      for (int r = 0; r < 4; ++r) alr[r] = __shfl(al, quad * 4 + r, 16);
      for (int dc = 0; dc < 4; ++dc)
        for (int r = 0; r < 4; ++r) zacc[dc][r] *= alr[r];
    }
    float p0[4], p1[4], acc = 0.f;
    for (int r = 0; r < 4; ++r) {
      p0[r] = __expf(s0[r] - mrow);
      p1[r] = __expf(s1[r] - mrow);
      acc += p0[r] + p1[r];
    }
    lsum += acc;
    uint2 wlo, whi;                     // P[q=lq][k]: pack 8 vals -> 4 dwords
    wlo.x = pk2(p0[0], p0[1]); wlo.y = pk2(p0[2], p0[3]);
    whi.x = pk2(p1[0], p1[1]); whi.y = pk2(p1[2], p1[3]);
    u16* rowp = &sPt[lq * 40 + quad * 4];
    *(uint2*)rowp        = wlo;         // ds_write_b64, k = quad*4..+3
    *(uint2*)(rowp + 16) = whi;         // ds_write_b64, k = 16+quad*4..+3
  };

  s8v kA[4], kB[4], vA[4], vB[4];
  LOADK(kA, 0);
  LOADV(vA, 0);
  if (nchunk > 1) LOADK(kB, 1);

  { // chunk 0: QK + softmax + P write for both tiles (PV deferred)
    f4v aA0 = {}, aA1 = {}, aB0 = {}, aB1 = {};
    aA0 = __builtin_amdgcn_mfma_f32_16x16x32_bf16(kA[0], qfA0, aA0, 0, 0, 0);
    aA0 = __builtin_amdgcn_mfma_f32_16x16x32_bf16(kA[1], qfA1, aA0, 0, 0, 0);
    aA1 = __builtin_amdgcn_mfma_f32_16x16x32_bf16(kA[2], qfA0, aA1, 0, 0, 0);
    aA1 = __builtin_amdgcn_mfma_f32_16x16x32_bf16(kA[3], qfA1, aA1, 0, 0, 0);
    aB0 = __builtin_amdgcn_mfma_f32_16x16x32_bf16(kA[0], qfB0, aB0, 0, 0, 0);
    aB0 = __builtin_amdgcn_mfma_f32_16x16x32_bf16(kA[1], qfB1, aB0, 0, 0, 0);
    aB1 = __builtin_amdgcn_mfma_f32_16x16x32_bf16(kA[2], qfB0, aB1, 0, 0, 0);
    aB1 = __builtin_amdgcn_mfma_f32_16x16x32_bf16(kA[3], qfB1, aB1, 0, 0, 0);
    SMW(0, qA, mA, lA, zA, sP[0][0], aA0, aA1);
    SMW(0, qB, mB, lB, zB, sP[1][0], aB0, aB1);
  }

  // pipeline step: QK(c) both tiles || PV(c-1) both tiles || softmax(c)+P(c)
  auto STEP = [&](int c, s8v (&kcur)[4], s8v (&knxt)[4],
                  s8v (&vpv)[4], s8v (&vnew)[4]) {
    if (c + 1 < nchunk) LOADK(knxt, c + 1);   // K for next iter
    LOADV(vnew, c);                           // V(c), consumed by next PV
    f4v aA0 = {}, aA1 = {}, aB0 = {}, aB1 = {};
    aA0 = __builtin_amdgcn_mfma_f32_16x16x32_bf16(kcur[0], qfA0, aA0, 0, 0, 0);
    aA0 = __builtin_amdgcn_mfma_f32_16x16x32_bf16(kcur[1], qfA1, aA0, 0, 0, 0);
    aA1 = __builtin_amdgcn_mfma_f32_16x16x32_bf16(kcur[2], qfA0, aA1, 0, 0, 0);
    aA1 = __builtin_amdgcn_mfma_f32_16x16x32_bf16(kcur[3], qfA1, aA1, 0, 0, 0);
    aB0 = __builtin_amdgcn_mfma_f32_16x16x32_bf16(kcur[0], qfB0, aB0, 0, 0, 0);
    aB0 = __builtin_amdgcn_mfma_f32_16x16x32_bf16(kcur[1], qfB1, aB0, 0, 0, 0);
    aB1 = __builtin_amdgcn_mfma_f32_16x16x32_bf16(kcur[2], qfB0, aB1, 0, 0, 0);
    aB1 = __builtin_amdgcn_mfma_f32_16x16x32_bf16(kcur[3], qfB1, aB1, 0, 0, 0);
    // PV(c-1): P written last iteration -> LDS latency hidden under QK
    s8v pfA = *(const s8v*)&sP[0][(c + 1) & 1][lq * 40 + quad * 8];
    s8v pfB = *(const s8v*)&sP[1][(c + 1) & 1][lq * 40 + quad * 8];
    for (int dc = 0; dc < 4; ++dc)
      zA[dc] = __builtin_amdgcn_mfma_f32_16x16x32_bf16(pfA, vpv[dc], zA[dc], 0, 0, 0);
    for (int dc = 0; dc < 4; ++dc)
      zB[dc] = __builtin_amdgcn_mfma_f32_16x16x32_bf16(pfB, vpv[dc], zB[dc], 0, 0, 0);
    SMW(c, qA, mA, lA, zA, sP[0][c & 1], aA0, aA1);
    SMW(c, qB, mB, lB, zB, sP[1][c & 1], aB0, aB1);
  };

  int c = 1;
  for (; c + 1 < nchunk; c += 2) {
    STEP(c,     kB, kA, vA, vB);
    STEP(c + 1, kA, kB, vB, vA);
  }
  if (c < nchunk) STEP(c, kB, kA, vA, vB);

  { // drain: PV(nchunk-1) for both tiles
    s8v pfA = *(const s8v*)&sP[0][(nchunk - 1) & 1][lq * 40 + quad * 8];
    s8v pfB = *(const s8v*)&sP[1][(nchunk - 1) & 1][lq * 40 + quad * 8];
    if ((nchunk - 1) & 1) {
      for (int dc = 0; dc < 4; ++dc) {
        zA[dc] = __builtin_amdgcn_mfma_f32_16x16x32_bf16(pfA, vB[dc], zA[dc], 0, 0, 0);
        zB[dc] = __builtin_amdgcn_mfma_f32_16x16x32_bf16(pfB, vB[dc], zB[dc], 0, 0, 0);
      }
    } else {
      for (int dc = 0; dc < 4; ++dc) {
        zA[dc] = __builtin_amdgcn_mfma_f32_16x16x32_bf16(pfA, vA[dc], zA[dc], 0, 0, 0);
        zB[dc] = __builtin_amdgcn_mfma_f32_16x16x32_bf16(pfB, vA[dc], zB[dc], 0, 0, 0);
      }
    }
  }
#undef LOADK
#undef LOADV

  // one-time sum reduction across the 4 quad-lanes of each row
  lA += __shfl_xor(lA, 16, 64); lA += __shfl_xor(lA, 32, 64);
  lB += __shfl_xor(lB, 16, 64); lB += __shfl_xor(lB, 32, 64);
  float invA[4], invB[4];
  for (int r = 0; r < 4; ++r) {
    invA[r] = 1.0f / __shfl(lA, quad * 4 + r, 16);
    invB[r] = 1.0f / __shfl(lB, quad * 4 + r, 16);
  }
  for (int dc = 0; dc < 4; ++dc)
    for (int r = 0; r < 4; ++r) {
      size_t rowA = (size_t)b * 2048 + qA + quad * 4 + r;
      size_t rowB = (size_t)b * 2048 + qB + quad * 4 + r;
      Z[rowA * 1024 + h * 64 + dc * 16 + lq] = f2b(zA[dc][r] * invA[r]);
      Z[rowB * 1024 + h * 64 + dc * 16 + lq] = f2b(zB[dc][r] * invB[r]);
    }
}

// ---------------------------------------------------------------------------
// Launch
// ---------------------------------------------------------------------------
extern "C" void kernel_launch(void* const* d_in, const int* in_sizes, int n_in,
                              void* d_out, int out_size, void* d_ws, size_t ws_size,
                              hipStream_t stream) {
  const float* x  = (const float*)d_in[0];
  const float* WQ = (const float*)d_in[1];
  const float* bQ = (const float*)d_in[2];
  const float* WK = (const float*)d_in[3];
  const float* bK = (const float*)d_in[4];
  const float* WV = (const float*)d_in[5];
  const float* WO = (const float*)d_in[6];
  const float* bV = (const float*)d_in[7];
  const float* bO = (const float*)d_in[8];
  float* out = (float*)d_out;

  uint8_t* ws = (uint8_t*)d_ws;
  u16*   xb    = (u16*)(ws);                       //  8 MB  [4096][1024] (dead after QKV GEMM)
  u16*   VTv   = (u16*)(ws);                       //  8 MB  [1024][4096] V^T (reuses xb)
  u16*   WTqkv = (u16*)(ws + 8388608);             //  6 MB  [3072][1024]
  u16*   WOT   = (u16*)(ws + 14680064);            //  2 MB  [1024][1024]
  u16*   QKV   = (u16*)(ws + 16777216);            // 24 MB  [4096][3072]
  u16*   Zb    = (u16*)(ws + 41943040);            //  8 MB  [4096][1024]
  float* bqkv  = (float*)(ws + 50331648);          // 12 KB
  float* bsum  = (float*)(ws + 50343936);          //  4 KB

  conv_x<<<4096, 256, 0, stream>>>(x, xb);
  convT_w<<<dim3(16, 16), 256, 0, stream>>>(WQ, WTqkv);
  convT_w<<<dim3(16, 16), 256, 0, stream>>>(WK, WTqkv + 1024 * 1024);
  convT_w<<<dim3(16, 16), 256, 0, stream>>>(WV, WTqkv + 2048 * 1024);
  convT_wo<<<dim3(16, 16), 256, 0, stream>>>(WO, WOT);
  conv_bias<<<16, 256, 0, stream>>>(bQ, bK, bV, bO, bqkv, bsum);

  // QKV projection: Q columns pre-scaled by 0.125 (exact in bf16)
  gemm_bt<false><<<dim3(24, 32), 256, 0, stream>>>(xb, WTqkv, bqkv, (void*)QKV, 3072, 1024, 1024);
  // V transpose (xb dead; VT reuses its workspace)
  convT_v<<<dim3(64, 16), 256, 0, stream>>>(QKV, VTv);
  // attention: 2048 one-wave blocks, 2 q-tiles each, XCD + heavy/light swizzle
  attn_fwd<<<dim3(2048, 1, 1), 64, 0, stream>>>(QKV, VTv, Zb);
  // output projection: [4096x1024] x [1024x1024] -> fp32 out (+ sum_h b_O)
  gemm_bt<true><<<dim3(8, 32), 256, 0, stream>>>(Zb, WOT, bsum, (void*)out, 1024, 1024, 0);
}

// Round 7
// 223.074 us; speedup vs baseline: 1.7961x; 1.0353x over previous
//
#include <hip/hip_runtime.h>
#include <cstdint>

typedef unsigned short u16;
typedef short s8v __attribute__((ext_vector_type(8)));
typedef float f4v __attribute__((ext_vector_type(4)));

// fp32 -> bf16 round-to-nearest-even (bit trick)
__device__ __forceinline__ u16 f2b(float f) {
  uint32_t u = __float_as_uint(f);
  u = (u + 0x7FFFu + ((u >> 16) & 1u)) >> 16;
  return (u16)u;
}

// pack two f32 -> bf16x2 (RNE) in one instruction (T12 recipe; no builtin)
__device__ __forceinline__ uint32_t pk2(float a, float b) {
  uint32_t r;
  asm("v_cvt_pk_bf16_f32 %0, %1, %2" : "=v"(r) : "v"(a), "v"(b));
  return r;
}

// async global->LDS, 16B per lane (wave-uniform LDS base + lane*16 layout)
__device__ __forceinline__ void gload16(const u16* g, u16* l) {
  __builtin_amdgcn_global_load_lds(
      (const __attribute__((address_space(1))) void*)g,
      (__attribute__((address_space(3))) void*)l, 16, 0, 0);
}

// ---------------------------------------------------------------------------
// Fused prep kernel: one launch replaces conv_x + 3x convT_w + convT_wo +
// conv_bias. Branch is block-uniform.
// blocks: [0,4096) conv_x | [4096,4864) convT_w | [4864,5120) convT_wo |
//         [5120,5136) conv_bias
// ---------------------------------------------------------------------------
__global__ void prep(const float* __restrict__ x, u16* __restrict__ xb,
                     const float* __restrict__ WQ, const float* __restrict__ WK,
                     const float* __restrict__ WV, const float* __restrict__ WO,
                     u16* __restrict__ WTqkv, u16* __restrict__ WOT,
                     const float* __restrict__ bQ, const float* __restrict__ bK,
                     const float* __restrict__ bV, const float* __restrict__ bO,
                     float* __restrict__ bqkv, float* __restrict__ bsum) {
  __shared__ u16 tile[64][65];
  const int bid = blockIdx.x;
  const int tid = threadIdx.x;

  if (bid < 4096) {                       // x fp32 -> bf16, 4 elems/thread
    int i = bid * 256 + tid;
    float4 v = ((const float4*)x)[i];
    uint2 o;
    o.x = (uint32_t)f2b(v.x) | ((uint32_t)f2b(v.y) << 16);
    o.y = (uint32_t)f2b(v.z) | ((uint32_t)f2b(v.w) << 16);
    ((uint2*)xb)[i] = o;
  } else if (bid < 4864) {                // W_{Q,K,V} -> WTqkv (B^T), 64x64 transpose
    int sub = bid - 4096;
    int w = sub >> 8, sub2 = sub & 255;
    const float* W = (w == 0) ? WQ : (w == 1) ? WK : WV;
    u16* dst = WTqkv + (size_t)w * 1024 * 1024;
    const int m0 = (sub2 & 15) * 64;
    const int h  = sub2 >> 4;
    const int c  = tid & 63;
    const int r4 = tid >> 6;
    const float* Wh = W + (size_t)h * 65536;
    for (int i = 0; i < 16; ++i) {
      int lm = i * 4 + r4;
      tile[lm][c] = f2b(Wh[(size_t)(m0 + lm) * 64 + c]);
    }
    __syncthreads();
    for (int i = 0; i < 16; ++i) {
      int dd = i * 4 + r4;
      dst[((size_t)h * 64 + dd) * 1024 + m0 + c] = tile[c][dd];
    }
  } else if (bid < 5120) {                // W_O flat [1024][1024] -> WOT[m][k]
    int sub = bid - 4864;
    const int k0 = (sub & 15) * 64;
    const int m0 = (sub >> 4) * 64;
    const int c  = tid & 63;
    const int r4 = tid >> 6;
    for (int i = 0; i < 16; ++i) {
      int lk = i * 4 + r4;
      tile[lk][c] = f2b(WO[(size_t)(k0 + lk) * 1024 + m0 + c]);
    }
    __syncthreads();
    for (int i = 0; i < 16; ++i) {
      int lm = i * 4 + r4;
      WOT[(size_t)(m0 + lm) * 1024 + k0 + c] = tile[c][lm];
    }
  } else {                                // biases
    int t = (bid - 5120) * 256 + tid;
    if (t < 1024)       bqkv[t] = bQ[t];
    else if (t < 2048)  bqkv[t] = bK[t - 1024];
    else if (t < 3072)  bqkv[t] = bV[t - 2048];
    else {
      int m = t - 3072;
      float s = 0.f;
      for (int hh = 0; hh < 16; ++hh) s += bO[hh * 1024 + m];
      bsum[m] = s;
    }
  }
}

// V columns of QKV [4096][3072] (cols 2048..3071) -> VT[(h*64+d)][token] bf16.
__global__ void convT_v(const u16* __restrict__ QKV, u16* __restrict__ VT) {
  __shared__ u16 tile[64][65];
  const int r0 = blockIdx.x * 64;   // token rows (0..4095)
  const int c0 = blockIdx.y * 64;   // v-feature cols (0..1023)
  const int c  = threadIdx.x & 63;
  const int r4 = threadIdx.x >> 6;
  for (int i = 0; i < 16; ++i) {
    int lr = i * 4 + r4;
    tile[lr][c] = QKV[(size_t)(r0 + lr) * 3072 + 2048 + c0 + c];  // coalesced read
  }
  __syncthreads();
  for (int i = 0; i < 16; ++i) {
    int lc = i * 4 + r4;
    VT[(size_t)(c0 + lc) * 4096 + r0 + c] = tile[c][lc];          // coalesced write
  }
}

// ---------------------------------------------------------------------------
// bf16 MFMA GEMM: C = (A * BT^T + bias[col]) * (col<scale_cols ? 0.125 : 1)
// 128x128 tile, BK=32, 4 waves. Staging via global_load_lds width=16.
// ---------------------------------------------------------------------------
template<bool OUT_F32>
__global__ void gemm_bt(const u16* __restrict__ A, const u16* __restrict__ BT,
                        const float* __restrict__ bias, void* __restrict__ Cout,
                        int N, int K, int scale_cols) {
  __shared__ __align__(16) u16 sA[128 * 32];
  __shared__ __align__(16) u16 sB[128 * 32];
  const int tid  = threadIdx.x;
  const int lane = tid & 63, wave = tid >> 6;
  const int wm = wave >> 1, wn = wave & 1;
  const int lq = lane & 15, quad = lane >> 4;
  const int m0 = blockIdx.y * 128, n0 = blockIdx.x * 128;

  f4v acc[4][4] = {};

  for (int k0 = 0; k0 < K; k0 += 32) {
    __syncthreads();
    for (int i = 0; i < 2; ++i) {
      int s = tid + i * 256;
      int row = s >> 2, part = s & 3;
      gload16(A  + (size_t)(m0 + row) * K + k0 + part * 8, &sA[s * 8]);
      gload16(BT + (size_t)(n0 + row) * K + k0 + part * 8, &sB[s * 8]);
    }
    __syncthreads();   // compiler drains vmcnt before barrier
    s8v af[4], bfr[4];
    for (int i = 0; i < 4; ++i)
      af[i]  = *(const s8v*)&sA[(wm * 64 + i * 16 + lq) * 32 + quad * 8];
    for (int j = 0; j < 4; ++j)
      bfr[j] = *(const s8v*)&sB[(wn * 64 + j * 16 + lq) * 32 + quad * 8];
    for (int i = 0; i < 4; ++i)
      for (int j = 0; j < 4; ++j)
        acc[i][j] = __builtin_amdgcn_mfma_f32_16x16x32_bf16(af[i], bfr[j], acc[i][j], 0, 0, 0);
  }

  for (int i = 0; i < 4; ++i)
    for (int j = 0; j < 4; ++j) {
      int row = m0 + wm * 64 + i * 16 + quad * 4;
      int col = n0 + wn * 64 + j * 16 + lq;
      float bb = bias[col];
      float sc = (col < scale_cols) ? 0.125f : 1.0f;
      for (int r = 0; r < 4; ++r) {
        float v = (acc[i][j][r] + bb) * sc;
        if (OUT_F32) ((float*)Cout)[(size_t)(row + r) * N + col] = v;
        else         ((u16*)Cout)[(size_t)(row + r) * N + col] = f2b(v);
      }
    }
}

// ---------------------------------------------------------------------------
// Flash attention (causal). 1 wave, 2 adjacent 16-query tiles, KVBLK=64.
// Round-7 = round-6 with the LDS hazard fixed:
//  * ping-pong sP restored (PV reads buf (c+1)&1, SMW writes buf c&1 —
//    1-iteration RAW distance, the round-5-proven structure). Round 6's
//    single buffer relied on compiler alias analysis connecting s8v loads
//    with uint2 stores at the same addresses; if disconnected, the P stores
//    can be reordered/DSE'd past the reads -> uninitialized-LDS reads (NaN).
//  * asm volatile("" ::: "memory") fences pin PV reads before SMW writes
//    and SMW writes before the next iteration's PV reads, independent of
//    TBAA. Zero instructions emitted.
// Kept from round 6: 64-key STEP (32 MFMA per softmax block), single
// K/V register buffers reloaded AFTER the MFMAs consume them (SSA-safe),
// s_setprio around the MFMA cluster, heavy+light CU pairing, fused prep.
// ---------------------------------------------------------------------------
__global__ __launch_bounds__(64, 2) void attn_fwd(const u16* __restrict__ QKV,
                                                  const u16* __restrict__ VT,
                                                  u16* __restrict__ Z) {
  __shared__ __align__(16) u16 sP[2][2][16 * 72];   // [tile][pingpong]
  const int lane = threadIdx.x;
  const int lq = lane & 15, quad = lane >> 4;

  const int id   = blockIdx.x;             // 0..2047
  const int xcd  = id & 7;
  const int slot = id >> 3;                // 0..255 per XCD
  const int g    = xcd + 8 * (slot >> 6);  // combo 0..31
  const int s    = slot & 63;
  const int u    = (s < 32) ? (63 - s) : (s - 32);  // heavy+light pairing
  const int h = g & 15, b = g >> 4;
  const int qA = u * 32, qB = qA + 16;
  const int nchunk = u / 2 + 1;            // 64-key chunks

  const int RS = 3072;
  const u16* base = QKV + (size_t)b * 2048 * RS;
  const u16* Qb  = base + h * 64;
  const u16* Kb  = base + 1024 + h * 64;
  const u16* VTb = VT + (size_t)h * 64 * 4096 + (size_t)b * 2048;

  // Q frags (B-operand): lane holds Q[q+lq][d = 32*half + quad*8 + j]
  s8v qfA0 = *(const s8v*)&Qb[(size_t)(qA + lq) * RS + quad * 8];
  s8v qfA1 = *(const s8v*)&Qb[(size_t)(qA + lq) * RS + 32 + quad * 8];
  s8v qfB0 = *(const s8v*)&Qb[(size_t)(qB + lq) * RS + quad * 8];
  s8v qfB1 = *(const s8v*)&Qb[(size_t)(qB + lq) * RS + 32 + quad * 8];

  f4v zA[4] = {}, zB[4] = {};
  float mA = -3.0e38f, lA = 0.f, mB = -3.0e38f, lB = 0.f;

  s8v kf[8], vf[8];   // single buffers: K rows / V cols of the current chunk

#define LOADK(c_) do {                                                        \
    const int kk0_ = (c_) * 64;                                               \
    _Pragma("unroll")                                                         \
    for (int i_ = 0; i_ < 4; ++i_) {                                          \
      const u16* kr_ = &Kb[(size_t)(kk0_ + 16 * i_ + lq) * RS + quad * 8];    \
      kf[2 * i_]     = *(const s8v*)kr_;                                      \
      kf[2 * i_ + 1] = *(const s8v*)(kr_ + 32);                               \
    }                                                                         \
  } while (0)

#define LOADV(c_) do {                                                        \
    const int kk0_ = (c_) * 64;                                               \
    _Pragma("unroll")                                                         \
    for (int d_ = 0; d_ < 4; ++d_) {                                          \
      const u16* vr_ = &VTb[(size_t)(d_ * 16 + lq) * 4096 + kk0_ + quad * 8]; \
      vf[d_]     = *(const s8v*)vr_;                                          \
      vf[d_ + 4] = *(const s8v*)(vr_ + 32);                                   \
    }                                                                         \
  } while (0)

  // softmax of 64-key chunk c for one tile (swapped layout) + packed P write
  auto SMW = [&](int c, int qt0, float& mrow, float& lsum, f4v (&zacc)[4],
                 u16* sPt, f4v (&sc)[4]) {
    float sv[4][4];
    for (int i = 0; i < 4; ++i)
      for (int r = 0; r < 4; ++r) sv[i][r] = sc[i][r];
    if (c + 1 == nchunk) {              // only the last chunk crosses the diagonal
      const int kb = c * 64;
      for (int i = 0; i < 4; ++i)
        for (int r = 0; r < 4; ++r)
          if (kb + 16 * i + quad * 4 + r > qt0 + lq) sv[i][r] = -3.0e38f;
    }
    float lmax = sv[0][0];
    for (int i = 0; i < 4; ++i)
      for (int r = 0; r < 4; ++r) lmax = fmaxf(lmax, sv[i][r]);
    if (!__all(lmax <= mrow + 8.0f)) {  // rare after warmup (defer-max, THR=8)
      float t = lmax;
      t = fmaxf(t, __shfl_xor(t, 16, 64));
      t = fmaxf(t, __shfl_xor(t, 32, 64));   // row max across the 4 quad-lanes
      float mnew = fmaxf(mrow, t);
      float al = __expf(mrow - mnew);
      mrow = mnew;
      lsum *= al;
      float alr[4];                     // zacc rows are q = quad*4+r
      for (int r = 0; r < 4; ++r) alr[r] = __shfl(al, quad * 4 + r, 16);
      for (int dc = 0; dc < 4; ++dc)
        for (int r = 0; r < 4; ++r) zacc[dc][r] *= alr[r];
    }
    float acc = 0.f;
    float p[4][4];
    for (int i = 0; i < 4; ++i)
      for (int r = 0; r < 4; ++r) {
        p[i][r] = __expf(sv[i][r] - mrow);
        acc += p[i][r];
      }
    lsum += acc;
    for (int i = 0; i < 4; ++i) {       // P[q=lq][k=16i+quad*4 ..+3]
      uint2 w;
      w.x = pk2(p[i][0], p[i][1]);
      w.y = pk2(p[i][2], p[i][3]);
      *(uint2*)&sPt[lq * 72 + 16 * i + quad * 4] = w;   // ds_write_b64
    }
  };

#define QK(aA_, aB_) do {                                                     \
    _Pragma("unroll")                                                         \
    for (int i_ = 0; i_ < 4; ++i_) {                                          \
      aA_[i_] = __builtin_amdgcn_mfma_f32_16x16x32_bf16(kf[2*i_],   qfA0, aA_[i_], 0, 0, 0); \
      aA_[i_] = __builtin_amdgcn_mfma_f32_16x16x32_bf16(kf[2*i_+1], qfA1, aA_[i_], 0, 0, 0); \
      aB_[i_] = __builtin_amdgcn_mfma_f32_16x16x32_bf16(kf[2*i_],   qfB0, aB_[i_], 0, 0, 0); \
      aB_[i_] = __builtin_amdgcn_mfma_f32_16x16x32_bf16(kf[2*i_+1], qfB1, aB_[i_], 0, 0, 0); \
    }                                                                         \
  } while (0)

  // PV from ping-pong buffer pb (P of the previous chunk) + current vf
  auto PV = [&](int pb) {
    s8v pA0 = *(const s8v*)&sP[0][pb][lq * 72 + quad * 8];
    s8v pA1 = *(const s8v*)&sP[0][pb][lq * 72 + 32 + quad * 8];
    s8v pB0 = *(const s8v*)&sP[1][pb][lq * 72 + quad * 8];
    s8v pB1 = *(const s8v*)&sP[1][pb][lq * 72 + 32 + quad * 8];
#pragma unroll
    for (int d_ = 0; d_ < 4; ++d_) {
      zA[d_] = __builtin_amdgcn_mfma_f32_16x16x32_bf16(pA0, vf[d_],     zA[d_], 0, 0, 0);
      zA[d_] = __builtin_amdgcn_mfma_f32_16x16x32_bf16(pA1, vf[d_ + 4], zA[d_], 0, 0, 0);
      zB[d_] = __builtin_amdgcn_mfma_f32_16x16x32_bf16(pB0, vf[d_],     zB[d_], 0, 0, 0);
      zB[d_] = __builtin_amdgcn_mfma_f32_16x16x32_bf16(pB1, vf[d_ + 4], zB[d_], 0, 0, 0);
    }
  };

  LOADK(0);
  { // chunk 0: QK + softmax + P write into buf 0 (PV deferred)
    f4v aA[4] = {}, aB[4] = {};
    __builtin_amdgcn_s_setprio(1);
    QK(aA, aB);
    __builtin_amdgcn_s_setprio(0);
    if (nchunk > 1) LOADK(1);
    LOADV(0);
    SMW(0, qA, mA, lA, zA, sP[0][0], aA);
    SMW(0, qB, mB, lB, zB, sP[1][0], aB);
    asm volatile("" ::: "memory");      // P(0) writes pinned before PV reads
  }

  for (int c = 1; c < nchunk; ++c) {
    f4v aA[4] = {}, aB[4] = {};
    __builtin_amdgcn_s_setprio(1);
    QK(aA, aB);                         // kf = K(c)
    PV((c + 1) & 1);                    // reads P(c-1) + vf = V(c-1)
    __builtin_amdgcn_s_setprio(0);
    asm volatile("" ::: "memory");      // PV reads pinned before SMW writes
    if (c + 1 < nchunk) LOADK(c + 1);   // safe: QK consumed kf at issue
    LOADV(c);                           // safe: PV consumed vf at issue
    SMW(c, qA, mA, lA, zA, sP[0][c & 1], aA);
    SMW(c, qB, mB, lB, zB, sP[1][c & 1], aB);
    asm volatile("" ::: "memory");      // P(c) writes pinned before next PV
  }

  { // drain: PV(nchunk-1) from the last-written buffer
    __builtin_amdgcn_s_setprio(1);
    PV((nchunk - 1) & 1);
    __builtin_amdgcn_s_setprio(0);
  }
#undef QK
#undef LOADK
#undef LOADV

  // one-time sum reduction across the 4 quad-lanes of each row
  lA += __shfl_xor(lA, 16, 64); lA += __shfl_xor(lA, 32, 64);
  lB += __shfl_xor(lB, 16, 64); lB += __shfl_xor(lB, 32, 64);
  float invA[4], invB[4];
  for (int r = 0; r < 4; ++r) {
    invA[r] = 1.0f / __shfl(lA, quad * 4 + r, 16);
    invB[r] = 1.0f / __shfl(lB, quad * 4 + r, 16);
  }
  for (int dc = 0; dc < 4; ++dc)
    for (int r = 0; r < 4; ++r) {
      size_t rowA = (size_t)b * 2048 + qA + quad * 4 + r;
      size_t rowB = (size_t)b * 2048 + qB + quad * 4 + r;
      Z[rowA * 1024 + h * 64 + dc * 16 + lq] = f2b(zA[dc][r] * invA[r]);
      Z[rowB * 1024 + h * 64 + dc * 16 + lq] = f2b(zB[dc][r] * invB[r]);
    }
}

// ---------------------------------------------------------------------------
// Launch
// ---------------------------------------------------------------------------
extern "C" void kernel_launch(void* const* d_in, const int* in_sizes, int n_in,
                              void* d_out, int out_size, void* d_ws, size_t ws_size,
                              hipStream_t stream) {
  const float* x  = (const float*)d_in[0];
  const float* WQ = (const float*)d_in[1];
  const float* bQ = (const float*)d_in[2];
  const float* WK = (const float*)d_in[3];
  const float* bK = (const float*)d_in[4];
  const float* WV = (const float*)d_in[5];
  const float* WO = (const float*)d_in[6];
  const float* bV = (const float*)d_in[7];
  const float* bO = (const float*)d_in[8];
  float* out = (float*)d_out;

  uint8_t* ws = (uint8_t*)d_ws;
  u16*   xb    = (u16*)(ws);                       //  8 MB  [4096][1024] (dead after QKV GEMM)
  u16*   VTv   = (u16*)(ws);                       //  8 MB  [1024][4096] V^T (reuses xb)
  u16*   WTqkv = (u16*)(ws + 8388608);             //  6 MB  [3072][1024]
  u16*   WOT   = (u16*)(ws + 14680064);            //  2 MB  [1024][1024]
  u16*   QKV   = (u16*)(ws + 16777216);            // 24 MB  [4096][3072]
  u16*   Zb    = (u16*)(ws + 41943040);            //  8 MB  [4096][1024]
  float* bqkv  = (float*)(ws + 50331648);          // 12 KB
  float* bsum  = (float*)(ws + 50343936);          //  4 KB

  // fused prep: conv_x + 3x convT_w + convT_wo + conv_bias
  prep<<<5136, 256, 0, stream>>>(x, xb, WQ, WK, WV, WO, WTqkv, WOT,
                                 bQ, bK, bV, bO, bqkv, bsum);
  // QKV projection: Q columns pre-scaled by 0.125 (exact in bf16)
  gemm_bt<false><<<dim3(24, 32), 256, 0, stream>>>(xb, WTqkv, bqkv, (void*)QKV, 3072, 1024, 1024);
  // V transpose (xb dead; VT reuses its workspace)
  convT_v<<<dim3(64, 16), 256, 0, stream>>>(QKV, VTv);
  // attention: 2048 one-wave blocks, 2 q-tiles each, KVBLK=64
  attn_fwd<<<dim3(2048, 1, 1), 64, 0, stream>>>(QKV, VTv, Zb);
  // output projection: [4096x1024] x [1024x1024] -> fp32 out (+ sum_h b_O)
  gemm_bt<true><<<dim3(8, 32), 256, 0, stream>>>(Zb, WOT, bsum, (void*)out, 1024, 1024, 0);
}